// Round 5
// baseline (330.348 us; speedup 1.0000x reference)
//
#include <hip/hip_runtime.h>
#include <math.h>

#define C 64
#define BN 128              // nodes per destination bucket
#define BSHIFT 7            // log2(BN)
#define NPART 256           // partition blocks
#define RMASK ((1 << 20) - 1)

__device__ __forceinline__ float sigf(float x) { return 1.0f / (1.0f + __expf(-x)); }

// ---- Kernel 1: W = max(lstm_fwd(conv_w), lstm_bwd(conv_w)) ----------------
__global__ __launch_bounds__(256) void lstm_w_kernel(
    const float* __restrict__ cw,
    const float* __restrict__ wf, const float* __restrict__ bif, const float* __restrict__ bhf,
    const float* __restrict__ wb, const float* __restrict__ bib, const float* __restrict__ bhb,
    float* __restrict__ W)
{
    int tid = blockIdx.x * blockDim.x + threadIdx.x;   // 0..4095
    int r = tid >> 6, c = tid & 63;
    const float* x = cw + r * C;

    const float* f_i = wf + (0 * C + c) * C;
    const float* f_g = wf + (2 * C + c) * C;
    const float* f_o = wf + (3 * C + c) * C;
    const float* b_i = wb + (0 * C + c) * C;
    const float* b_g = wb + (2 * C + c) * C;
    const float* b_o = wb + (3 * C + c) * C;

    float zif = 0.f, zgf = 0.f, zof = 0.f, zib = 0.f, zgb = 0.f, zob = 0.f;
    #pragma unroll
    for (int k = 0; k < C; ++k) {
        float xv = x[k];
        zif = fmaf(xv, f_i[k], zif);
        zgf = fmaf(xv, f_g[k], zgf);
        zof = fmaf(xv, f_o[k], zof);
        zib = fmaf(xv, b_i[k], zib);
        zgb = fmaf(xv, b_g[k], zgb);
        zob = fmaf(xv, b_o[k], zob);
    }
    zif += bif[0 * C + c] + bhf[0 * C + c];
    zgf += bif[2 * C + c] + bhf[2 * C + c];
    zof += bif[3 * C + c] + bhf[3 * C + c];
    zib += bib[0 * C + c] + bhb[0 * C + c];
    zgb += bib[2 * C + c] + bhb[2 * C + c];
    zob += bib[3 * C + c] + bhb[3 * C + c];

    float cf = sigf(zif) * tanhf(zgf);
    float hf = sigf(zof) * tanhf(cf);
    float cb = sigf(zib) * tanhf(zgb);
    float hb = sigf(zob) * tanhf(cb);
    W[tid] = fmaxf(hf, hb);
}

// ---- Kernel 2: per-block bucket histogram (LDS atomics only) --------------
__global__ __launch_bounds__(256) void hist_kernel(
    const int* __restrict__ col, int* __restrict__ hist,
    int E, int nbuck, int epb)
{
    __shared__ int h[1024];
    int t = threadIdx.x, b = blockIdx.x;
    for (int i = t; i < nbuck; i += 256) h[i] = 0;
    __syncthreads();
    int base = b * epb;
    int end = min(base + epb, E);
    for (int e = base + t; e < end; e += 256)
        atomicAdd(&h[col[e] >> BSHIFT], 1);
    __syncthreads();
    for (int i = t; i < nbuck; i += 256) hist[b * nbuck + i] = h[i];
}

// ---- Kernel 3: per-bucket exclusive scan over blocks (in place) -----------
__global__ __launch_bounds__(256) void scan_blocks_kernel(
    int* __restrict__ hist, int* __restrict__ bb, int nbuck)
{
    int k = blockIdx.x * 256 + threadIdx.x;
    if (k >= nbuck) return;
    int run = 0;
    for (int b = 0; b < NPART; ++b) {
        int v = hist[b * nbuck + k];
        hist[b * nbuck + k] = run;
        run += v;
    }
    bb[k] = run;
}

// ---- Kernel 4: exclusive scan of bucket totals (single block) -------------
__global__ __launch_bounds__(256) void scan_spine_kernel(
    int* __restrict__ bb, int nbuck, int E)
{
    __shared__ int wsum[4];
    int t = threadIdx.x;
    int base = t * 4;
    int v[4];
    #pragma unroll
    for (int j = 0; j < 4; ++j) {
        int idx = base + j;
        v[j] = (idx < nbuck) ? bb[idx] : 0;
    }
    int tsum = v[0] + v[1] + v[2] + v[3];
    int lane = t & 63, wid = t >> 6;
    int x = tsum;
    #pragma unroll
    for (int d = 1; d < 64; d <<= 1) {
        int y = __shfl_up(x, d, 64);
        if (lane >= d) x += y;
    }
    if (lane == 63) wsum[wid] = x;
    __syncthreads();
    if (t == 0) {
        int run = 0;
        #pragma unroll
        for (int w = 0; w < 4; ++w) { int z = wsum[w]; wsum[w] = run; run += z; }
    }
    __syncthreads();
    int run = x - tsum + wsum[wid];
    #pragma unroll
    for (int j = 0; j < 4; ++j) {
        int idx = base + j;
        if (idx < nbuck) bb[idx] = run;
        run += v[j];
    }
    if (t == 0) bb[nbuck] = E;
}

// ---- Kernel 5: partition — scatter {row|ld<<20, w} into bucket ranges -----
__global__ __launch_bounds__(256) void partition_kernel(
    const int* __restrict__ row, const int* __restrict__ col,
    const float* __restrict__ ew, const int* __restrict__ hist,
    const int* __restrict__ bb, int2* __restrict__ payload,
    int E, int nbuck, int epb)
{
    __shared__ int cur[1024];
    int t = threadIdx.x, b = blockIdx.x;
    for (int i = t; i < nbuck; i += 256)
        cur[i] = hist[b * nbuck + i] + bb[i];
    __syncthreads();
    int base = b * epb;
    int end = min(base + epb, E);
    for (int e = base + t; e < end; e += 256) {
        int c = col[e];
        int k = c >> BSHIFT;
        int pos = atomicAdd(&cur[k], 1);
        payload[pos] = make_int2(row[e] | ((c & (BN - 1)) << 20),
                                 __float_as_int(ew[e]));
    }
}

// ---- Kernel 6: per-bucket counting sort by node + deg/dinv + fold dinv[dst]
// Out: payload2 {row, w*dinv[dst]} sorted by dst node; seg[n]={start,count};
//      dinv[n] global.
__global__ __launch_bounds__(256) void sort_bucket_kernel(
    const int2* __restrict__ payload, const int* __restrict__ bb,
    int2* __restrict__ payload2, float* __restrict__ dinv,
    int2* __restrict__ seg, int N)
{
    __shared__ int bin[BN];
    __shared__ int bbase[BN];
    __shared__ int cur[BN];
    __shared__ float degl[BN];
    __shared__ float dinvl[BN];
    int t = threadIdx.x, k = blockIdx.x;
    if (t < BN) { bin[t] = 0; degl[t] = 0.f; }
    __syncthreads();

    int e0 = bb[k], e1 = bb[k + 1];
    for (int e = e0 + t; e < e1; e += 256) {
        int2 p = payload[e];
        int ld = p.x >> 20;
        atomicAdd(&bin[ld], 1);
        atomicAdd(&degl[ld], __int_as_float(p.y));
    }
    __syncthreads();

    // exclusive scan of bin[0..127] in wave 0 (2 bins per lane)
    if (t < 64) {
        int a = bin[2 * t], b2 = bin[2 * t + 1];
        int s = a + b2;
        int x = s;
        #pragma unroll
        for (int d = 1; d < 64; d <<= 1) {
            int y = __shfl_up(x, d, 64);
            if (t >= d) x += y;
        }
        int excl = x - s;
        bbase[2 * t] = excl;
        bbase[2 * t + 1] = excl + a;
    }
    __syncthreads();

    if (t < BN) {
        int n = k * BN + t;
        float di = rsqrtf(degl[t] + 1.0f);    // +1 self-loop weight
        dinvl[t] = di;
        cur[t] = e0 + bbase[t];
        if (n < N) {
            dinv[n] = di;
            seg[n] = make_int2(e0 + bbase[t], bin[t]);
        }
    }
    __syncthreads();

    for (int e = e0 + t; e < e1; e += 256) {
        int2 p = payload[e];
        int ld = p.x >> 20;
        int pos = atomicAdd(&cur[ld], 1);
        payload2[pos] = make_int2(p.x & RMASK,
                                  __float_as_int(__int_as_float(p.y) * dinvl[ld]));
    }
}

// ---- Kernel 7: Xw' = dinv ⊙ (X @ W)  (row-scaled, 32 rows/block) ----------
__global__ __launch_bounds__(256) void gemm_xw_kernel(
    const float* __restrict__ X, const float* __restrict__ W,
    const float* __restrict__ dinv, float* __restrict__ Y, int N)
{
    __shared__ float Wl[C * C];
    __shared__ float xl[32][C];
    int t = threadIdx.x;
    #pragma unroll
    for (int i = 0; i < 4; ++i)
        *(float4*)(Wl + 4 * (t + i * 256)) = *(const float4*)(W + 4 * (t + i * 256));

    int n0 = blockIdx.x * 32;
    #pragma unroll
    for (int i = 0; i < 2; ++i) {
        int idx = t + i * 256;            // 0..511 : (row, float4-group)
        int rr = idx >> 4, cc = (idx & 15) << 2;
        int n = n0 + rr;
        float4 v = (n < N) ? *(const float4*)(X + (size_t)n * C + cc)
                           : make_float4(0.f, 0.f, 0.f, 0.f);
        *(float4*)(&xl[rr][cc]) = v;
    }
    __syncthreads();

    int c = t & 63, rb = (t >> 6) * 8;
    float acc[8] = {0.f, 0.f, 0.f, 0.f, 0.f, 0.f, 0.f, 0.f};
    for (int k = 0; k < C; ++k) {
        float w = Wl[k * C + c];
        #pragma unroll
        for (int q = 0; q < 8; ++q) acc[q] = fmaf(xl[rb + q][k], w, acc[q]);
    }
    #pragma unroll
    for (int q = 0; q < 8; ++q) {
        int n = n0 + rb + q;
        if (n < N) Y[(size_t)n * C + c] = acc[q] * dinv[n];   // fold dinv[src]
    }
}

// ---- Kernel 8: gather-reduce (4-wide ILP) + fused fusion GEMM -------------
// row[n] = ne + ce + dinv[n]*Xw'[n] + sum_seg pn * Xw'[src]
// out[n] = row[n] @ fW^T + fb         (Xw' already has dinv[src] folded)
__global__ __launch_bounds__(256) void reduce_fused_kernel(
    const int2* __restrict__ seg, const int2* __restrict__ payload2,
    const float* __restrict__ Xw, const float* __restrict__ dinv,
    const float* __restrict__ ne, const float* __restrict__ ce,
    const float* __restrict__ fW, const float* __restrict__ fb,
    float* __restrict__ out, int N)
{
    __shared__ float Wt[C][C + 1];    // Wt[k][j] = fW[j*C+k]
    __shared__ float rowl[16][C];
    int t = threadIdx.x;
    #pragma unroll
    for (int i = 0; i < 16; ++i) {
        int idx = t + i * 256;
        Wt[idx & 63][idx >> 6] = fW[idx];
    }

    int g = t >> 4, lg = t & 15;
    int n = blockIdx.x * 16 + g;
    int cg = lg << 2;

    if (n < N) {
        int2 s = seg[n];
        int p = s.x, cnt = s.y;
        float4 a0 = make_float4(0.f, 0.f, 0.f, 0.f);
        float4 a1 = a0, a2 = a0, a3 = a0;
        while (cnt >= 4) {
            int2 p0 = payload2[p];
            int2 p1 = payload2[p + 1];
            int2 p2 = payload2[p + 2];
            int2 p3 = payload2[p + 3];
            const float4 v0 = *(const float4*)(Xw + (size_t)p0.x * C + cg);
            const float4 v1 = *(const float4*)(Xw + (size_t)p1.x * C + cg);
            const float4 v2 = *(const float4*)(Xw + (size_t)p2.x * C + cg);
            const float4 v3 = *(const float4*)(Xw + (size_t)p3.x * C + cg);
            float n0 = __int_as_float(p0.y), n1 = __int_as_float(p1.y);
            float n2 = __int_as_float(p2.y), n3 = __int_as_float(p3.y);
            a0.x = fmaf(v0.x, n0, a0.x); a0.y = fmaf(v0.y, n0, a0.y);
            a0.z = fmaf(v0.z, n0, a0.z); a0.w = fmaf(v0.w, n0, a0.w);
            a1.x = fmaf(v1.x, n1, a1.x); a1.y = fmaf(v1.y, n1, a1.y);
            a1.z = fmaf(v1.z, n1, a1.z); a1.w = fmaf(v1.w, n1, a1.w);
            a2.x = fmaf(v2.x, n2, a2.x); a2.y = fmaf(v2.y, n2, a2.y);
            a2.z = fmaf(v2.z, n2, a2.z); a2.w = fmaf(v2.w, n2, a2.w);
            a3.x = fmaf(v3.x, n3, a3.x); a3.y = fmaf(v3.y, n3, a3.y);
            a3.z = fmaf(v3.z, n3, a3.z); a3.w = fmaf(v3.w, n3, a3.w);
            p += 4; cnt -= 4;
        }
        while (cnt > 0) {
            int2 pl = payload2[p];
            float nn = __int_as_float(pl.y);
            const float4 v = *(const float4*)(Xw + (size_t)pl.x * C + cg);
            a0.x = fmaf(v.x, nn, a0.x); a0.y = fmaf(v.y, nn, a0.y);
            a0.z = fmaf(v.z, nn, a0.z); a0.w = fmaf(v.w, nn, a0.w);
            ++p; --cnt;
        }
        float di = dinv[n];
        size_t o = (size_t)n * C + cg;
        const float4 xv = *(const float4*)(Xw + o);   // Xw' = dinv[n]*Xw
        const float4 nv = *(const float4*)(ne + o);
        const float4 cv = *(const float4*)(ce + o);
        a0.x += a1.x + a2.x + a3.x + nv.x + cv.x + xv.x * di;
        a0.y += a1.y + a2.y + a3.y + nv.y + cv.y + xv.y * di;
        a0.z += a1.z + a2.z + a3.z + nv.z + cv.z + xv.z * di;
        a0.w += a1.w + a2.w + a3.w + nv.w + cv.w + xv.w * di;
        *(float4*)(&rowl[g][cg]) = a0;
    }
    __syncthreads();

    // fused 16x64 @ 64x64 GEMM from LDS
    int j = t & 63, r0 = (t >> 6) * 4;
    float bj = fb[j];
    float acc[4] = {bj, bj, bj, bj};
    for (int k = 0; k < C; ++k) {
        float w = Wt[k][j];
        #pragma unroll
        for (int q = 0; q < 4; ++q) acc[q] = fmaf(rowl[r0 + q][k], w, acc[q]);
    }
    #pragma unroll
    for (int q = 0; q < 4; ++q) {
        int nn = blockIdx.x * 16 + r0 + q;
        if (nn < N) out[(size_t)nn * C + j] = acc[q];
    }
}

extern "C" void kernel_launch(void* const* d_in, const int* in_sizes, int n_in,
                              void* d_out, int out_size, void* d_ws, size_t ws_size,
                              hipStream_t stream)
{
    const float* X        = (const float*)d_in[0];
    const int*   ei       = (const int*)d_in[1];
    const float* ew       = (const float*)d_in[2];
    const float* node_emb = (const float*)d_in[3];
    const float* com_emb  = (const float*)d_in[4];
    const float* cw       = (const float*)d_in[5];
    const float* w_ih_f   = (const float*)d_in[6];
    const float* b_ih_f   = (const float*)d_in[7];
    const float* b_hh_f   = (const float*)d_in[8];
    const float* w_ih_b   = (const float*)d_in[9];
    const float* b_ih_b   = (const float*)d_in[10];
    const float* b_hh_b   = (const float*)d_in[11];
    const float* fW       = (const float*)d_in[12];
    const float* fb       = (const float*)d_in[13];
    float* out = (float*)d_out;

    const int N = in_sizes[0] / C;
    const int E = in_sizes[2];
    const int* row = ei;               // edge_index[0]
    const int* col = ei + E;           // edge_index[1]
    const int nbuck = (N + BN - 1) / BN;
    const int epb = (E + NPART - 1) / NPART;

    // ---- workspace layout ----
    // [W][dinv][bb][seg][payload2: E*8][XwBuf: N*C*4]
    // pass-1 payload + hist alias INTO XwBuf (dead before gemm_xw writes it).
    char* wsb = (char*)d_ws;
    size_t o = 0;
    auto alloc = [&](size_t bytes) { void* p = wsb + o; o = (o + bytes + 15) & ~(size_t)15; return p; };
    float* W        = (float*)alloc((size_t)C * C * sizeof(float));      // 16 KB
    float* dinv     = (float*)alloc((size_t)N * sizeof(float));          // 400 KB
    int*   bb       = (int*)  alloc((size_t)(nbuck + 1) * sizeof(int));  // 3 KB
    int2*  seg      = (int2*) alloc((size_t)N * sizeof(int2));           // 800 KB
    int2*  payload2 = (int2*) alloc((size_t)E * sizeof(int2));           // 12.8 MB
    float* XwBuf    = (float*)alloc((size_t)N * C * sizeof(float));      // 25.6 MB
    int2*  payload  = (int2*)XwBuf;                       // 12.8 MB alias
    int*   hist     = (int*)(XwBuf + (size_t)E * 2);      // 800 KB alias after payload

    lstm_w_kernel<<<(C * C) / 256, 256, 0, stream>>>(
        cw, w_ih_f, b_ih_f, b_hh_f, w_ih_b, b_ih_b, b_hh_b, W);

    hist_kernel<<<NPART, 256, 0, stream>>>(col, hist, E, nbuck, epb);
    scan_blocks_kernel<<<(nbuck + 255) / 256, 256, 0, stream>>>(hist, bb, nbuck);
    scan_spine_kernel<<<1, 256, 0, stream>>>(bb, nbuck, E);
    partition_kernel<<<NPART, 256, 0, stream>>>(
        row, col, ew, hist, bb, payload, E, nbuck, epb);

    sort_bucket_kernel<<<nbuck, 256, 0, stream>>>(
        payload, bb, payload2, dinv, seg, N);

    gemm_xw_kernel<<<(N + 31) / 32, 256, 0, stream>>>(X, W, dinv, XwBuf, N);

    reduce_fused_kernel<<<(N + 15) / 16, 256, 0, stream>>>(
        seg, payload2, XwBuf, dinv, node_emb, com_emb, fW, fb, out, N);
}

// Round 6
// 225.617 us; speedup vs baseline: 1.4642x; 1.4642x over previous
//
#include <hip/hip_runtime.h>
#include <math.h>

#define C 64
#define BN 128              // nodes per destination bucket
#define BSHIFT 7            // log2(BN)
#define NPART 256           // partition blocks
#define RMASK ((1 << 20) - 1)

__device__ __forceinline__ float sigf(float x) { return 1.0f / (1.0f + __expf(-x)); }

// ---- Kernel 1: W = max(lstm_fwd(conv_w), lstm_bwd(conv_w)) ----------------
__global__ __launch_bounds__(256) void lstm_w_kernel(
    const float* __restrict__ cw,
    const float* __restrict__ wf, const float* __restrict__ bif, const float* __restrict__ bhf,
    const float* __restrict__ wb, const float* __restrict__ bib, const float* __restrict__ bhb,
    float* __restrict__ W)
{
    int tid = blockIdx.x * blockDim.x + threadIdx.x;   // 0..4095
    int r = tid >> 6, c = tid & 63;
    const float* x = cw + r * C;

    const float* f_i = wf + (0 * C + c) * C;
    const float* f_g = wf + (2 * C + c) * C;
    const float* f_o = wf + (3 * C + c) * C;
    const float* b_i = wb + (0 * C + c) * C;
    const float* b_g = wb + (2 * C + c) * C;
    const float* b_o = wb + (3 * C + c) * C;

    float zif = 0.f, zgf = 0.f, zof = 0.f, zib = 0.f, zgb = 0.f, zob = 0.f;
    #pragma unroll
    for (int k = 0; k < C; ++k) {
        float xv = x[k];
        zif = fmaf(xv, f_i[k], zif);
        zgf = fmaf(xv, f_g[k], zgf);
        zof = fmaf(xv, f_o[k], zof);
        zib = fmaf(xv, b_i[k], zib);
        zgb = fmaf(xv, b_g[k], zgb);
        zob = fmaf(xv, b_o[k], zob);
    }
    zif += bif[0 * C + c] + bhf[0 * C + c];
    zgf += bif[2 * C + c] + bhf[2 * C + c];
    zof += bif[3 * C + c] + bhf[3 * C + c];
    zib += bib[0 * C + c] + bhb[0 * C + c];
    zgb += bib[2 * C + c] + bhb[2 * C + c];
    zob += bib[3 * C + c] + bhb[3 * C + c];

    float cf = sigf(zif) * tanhf(zgf);
    float hf = sigf(zof) * tanhf(cf);
    float cb = sigf(zib) * tanhf(zgb);
    float hb = sigf(zob) * tanhf(cb);
    W[tid] = fmaxf(hf, hb);
}

// ---- Kernel 2: per-block bucket histogram (LDS atomics only) --------------
__global__ __launch_bounds__(256) void hist_kernel(
    const int* __restrict__ col, int* __restrict__ hist,
    int E, int nbuck, int epb)
{
    __shared__ int h[1024];
    int t = threadIdx.x, b = blockIdx.x;
    for (int i = t; i < nbuck; i += 256) h[i] = 0;
    __syncthreads();
    int base = b * epb;
    int end = min(base + epb, E);
    for (int e = base + t; e < end; e += 256)
        atomicAdd(&h[col[e] >> BSHIFT], 1);
    __syncthreads();
    for (int i = t; i < nbuck; i += 256) hist[b * nbuck + i] = h[i];
}

// ---- Kernel 3: per-bucket exclusive scan over blocks (in place) -----------
__global__ __launch_bounds__(256) void scan_blocks_kernel(
    int* __restrict__ hist, int* __restrict__ bb, int nbuck)
{
    int k = blockIdx.x * 256 + threadIdx.x;
    if (k >= nbuck) return;
    int run = 0;
    for (int b = 0; b < NPART; ++b) {
        int v = hist[b * nbuck + k];
        hist[b * nbuck + k] = run;
        run += v;
    }
    bb[k] = run;
}

// ---- Kernel 4: exclusive scan of bucket totals (single block) -------------
__global__ __launch_bounds__(256) void scan_spine_kernel(
    int* __restrict__ bb, int nbuck, int E)
{
    __shared__ int wsum[4];
    int t = threadIdx.x;
    int base = t * 4;
    int v[4];
    #pragma unroll
    for (int j = 0; j < 4; ++j) {
        int idx = base + j;
        v[j] = (idx < nbuck) ? bb[idx] : 0;
    }
    int tsum = v[0] + v[1] + v[2] + v[3];
    int lane = t & 63, wid = t >> 6;
    int x = tsum;
    #pragma unroll
    for (int d = 1; d < 64; d <<= 1) {
        int y = __shfl_up(x, d, 64);
        if (lane >= d) x += y;
    }
    if (lane == 63) wsum[wid] = x;
    __syncthreads();
    if (t == 0) {
        int run = 0;
        #pragma unroll
        for (int w = 0; w < 4; ++w) { int z = wsum[w]; wsum[w] = run; run += z; }
    }
    __syncthreads();
    int run = x - tsum + wsum[wid];
    #pragma unroll
    for (int j = 0; j < 4; ++j) {
        int idx = base + j;
        if (idx < nbuck) bb[idx] = run;
        run += v[j];
    }
    if (t == 0) bb[nbuck] = E;
}

// ---- Kernel 5: partition — scatter {row|ld<<20, w} into bucket ranges -----
__global__ __launch_bounds__(256) void partition_kernel(
    const int* __restrict__ row, const int* __restrict__ col,
    const float* __restrict__ ew, const int* __restrict__ hist,
    const int* __restrict__ bb, int2* __restrict__ payload,
    int E, int nbuck, int epb)
{
    __shared__ int cur[1024];
    int t = threadIdx.x, b = blockIdx.x;
    for (int i = t; i < nbuck; i += 256)
        cur[i] = hist[b * nbuck + i] + bb[i];
    __syncthreads();
    int base = b * epb;
    int end = min(base + epb, E);
    for (int e = base + t; e < end; e += 256) {
        int c = col[e];
        int k = c >> BSHIFT;
        int pos = atomicAdd(&cur[k], 1);
        payload[pos] = make_int2(row[e] | ((c & (BN - 1)) << 20),
                                 __float_as_int(ew[e]));
    }
}

// ---- Kernel 6: per-bucket counting sort by node + deg/dinv + fold dinv[dst]
// Out: payload2 {row, w*dinv[dst]} sorted by dst node; seg[n]={start,count};
//      dinv[n] global.
__global__ __launch_bounds__(256) void sort_bucket_kernel(
    const int2* __restrict__ payload, const int* __restrict__ bb,
    int2* __restrict__ payload2, float* __restrict__ dinv,
    int2* __restrict__ seg, int N)
{
    __shared__ int bin[BN];
    __shared__ int bbase[BN];
    __shared__ int cur[BN];
    __shared__ float degl[BN];
    __shared__ float dinvl[BN];
    int t = threadIdx.x, k = blockIdx.x;
    if (t < BN) { bin[t] = 0; degl[t] = 0.f; }
    __syncthreads();

    int e0 = bb[k], e1 = bb[k + 1];
    for (int e = e0 + t; e < e1; e += 256) {
        int2 p = payload[e];
        int ld = p.x >> 20;
        atomicAdd(&bin[ld], 1);
        atomicAdd(&degl[ld], __int_as_float(p.y));
    }
    __syncthreads();

    // exclusive scan of bin[0..127] in wave 0 (2 bins per lane)
    if (t < 64) {
        int a = bin[2 * t], b2 = bin[2 * t + 1];
        int s = a + b2;
        int x = s;
        #pragma unroll
        for (int d = 1; d < 64; d <<= 1) {
            int y = __shfl_up(x, d, 64);
            if (t >= d) x += y;
        }
        int excl = x - s;
        bbase[2 * t] = excl;
        bbase[2 * t + 1] = excl + a;
    }
    __syncthreads();

    if (t < BN) {
        int n = k * BN + t;
        float di = rsqrtf(degl[t] + 1.0f);    // +1 self-loop weight
        dinvl[t] = di;
        cur[t] = e0 + bbase[t];
        if (n < N) {
            dinv[n] = di;
            seg[n] = make_int2(e0 + bbase[t], bin[t]);
        }
    }
    __syncthreads();

    for (int e = e0 + t; e < e1; e += 256) {
        int2 p = payload[e];
        int ld = p.x >> 20;
        int pos = atomicAdd(&cur[ld], 1);
        payload2[pos] = make_int2(p.x & RMASK,
                                  __float_as_int(__int_as_float(p.y) * dinvl[ld]));
    }
}

// ---- Kernel 7: Xw' = dinv ⊙ (X @ W)  (row-scaled, 32 rows/block) ----------
__global__ __launch_bounds__(256) void gemm_xw_kernel(
    const float* __restrict__ X, const float* __restrict__ W,
    const float* __restrict__ dinv, float* __restrict__ Y, int N)
{
    __shared__ float Wl[C * C];
    __shared__ float xl[32][C];
    int t = threadIdx.x;
    #pragma unroll
    for (int i = 0; i < 4; ++i)
        *(float4*)(Wl + 4 * (t + i * 256)) = *(const float4*)(W + 4 * (t + i * 256));

    int n0 = blockIdx.x * 32;
    #pragma unroll
    for (int i = 0; i < 2; ++i) {
        int idx = t + i * 256;            // 0..511 : (row, float4-group)
        int rr = idx >> 4, cc = (idx & 15) << 2;
        int n = n0 + rr;
        float4 v = (n < N) ? *(const float4*)(X + (size_t)n * C + cc)
                           : make_float4(0.f, 0.f, 0.f, 0.f);
        *(float4*)(&xl[rr][cc]) = v;
    }
    __syncthreads();

    int c = t & 63, rb = (t >> 6) * 8;
    float acc[8] = {0.f, 0.f, 0.f, 0.f, 0.f, 0.f, 0.f, 0.f};
    for (int k = 0; k < C; ++k) {
        float w = Wl[k * C + c];
        #pragma unroll
        for (int q = 0; q < 8; ++q) acc[q] = fmaf(xl[rb + q][k], w, acc[q]);
    }
    #pragma unroll
    for (int q = 0; q < 8; ++q) {
        int n = n0 + rb + q;
        if (n < N) Y[(size_t)n * C + c] = acc[q] * dinv[n];   // fold dinv[src]
    }
}

// ---- Kernel 8: gather-reduce, 16 lanes/node, 4-wide ILP, no atomics -------
// tmp[n] = ne + ce + dinv[n]*Xw'[n] + sum_seg pn * Xw'[src]
__global__ __launch_bounds__(256) void reduce_kernel(
    const int2* __restrict__ seg, const int2* __restrict__ payload2,
    const float* __restrict__ Xw, const float* __restrict__ dinv,
    const float* __restrict__ ne, const float* __restrict__ ce,
    float* __restrict__ tmp, int N)
{
    int t = blockIdx.x * 256 + threadIdx.x;
    int n = t >> 4;
    if (n >= N) return;
    int cg = (t & 15) << 2;

    int2 s = seg[n];
    int p = s.x, cnt = s.y;
    float4 a0 = make_float4(0.f, 0.f, 0.f, 0.f);
    float4 a1 = a0, a2 = a0, a3 = a0;
    while (cnt >= 4) {
        int2 p0 = payload2[p];
        int2 p1 = payload2[p + 1];
        int2 p2 = payload2[p + 2];
        int2 p3 = payload2[p + 3];
        const float4 v0 = *(const float4*)(Xw + (size_t)p0.x * C + cg);
        const float4 v1 = *(const float4*)(Xw + (size_t)p1.x * C + cg);
        const float4 v2 = *(const float4*)(Xw + (size_t)p2.x * C + cg);
        const float4 v3 = *(const float4*)(Xw + (size_t)p3.x * C + cg);
        float n0 = __int_as_float(p0.y), n1 = __int_as_float(p1.y);
        float n2 = __int_as_float(p2.y), n3 = __int_as_float(p3.y);
        a0.x = fmaf(v0.x, n0, a0.x); a0.y = fmaf(v0.y, n0, a0.y);
        a0.z = fmaf(v0.z, n0, a0.z); a0.w = fmaf(v0.w, n0, a0.w);
        a1.x = fmaf(v1.x, n1, a1.x); a1.y = fmaf(v1.y, n1, a1.y);
        a1.z = fmaf(v1.z, n1, a1.z); a1.w = fmaf(v1.w, n1, a1.w);
        a2.x = fmaf(v2.x, n2, a2.x); a2.y = fmaf(v2.y, n2, a2.y);
        a2.z = fmaf(v2.z, n2, a2.z); a2.w = fmaf(v2.w, n2, a2.w);
        a3.x = fmaf(v3.x, n3, a3.x); a3.y = fmaf(v3.y, n3, a3.y);
        a3.z = fmaf(v3.z, n3, a3.z); a3.w = fmaf(v3.w, n3, a3.w);
        p += 4; cnt -= 4;
    }
    while (cnt > 0) {
        int2 pl = payload2[p];
        float nn = __int_as_float(pl.y);
        const float4 v = *(const float4*)(Xw + (size_t)pl.x * C + cg);
        a0.x = fmaf(v.x, nn, a0.x); a0.y = fmaf(v.y, nn, a0.y);
        a0.z = fmaf(v.z, nn, a0.z); a0.w = fmaf(v.w, nn, a0.w);
        ++p; --cnt;
    }
    float di = dinv[n];
    size_t o = (size_t)n * C + cg;
    const float4 xv = *(const float4*)(Xw + o);   // Xw' = dinv[n]*(X@W)[n]
    const float4 nv = *(const float4*)(ne + o);
    const float4 cv = *(const float4*)(ce + o);
    a0.x += a1.x + a2.x + a3.x + nv.x + cv.x + xv.x * di;
    a0.y += a1.y + a2.y + a3.y + nv.y + cv.y + xv.y * di;
    a0.z += a1.z + a2.z + a3.z + nv.z + cv.z + xv.z * di;
    a0.w += a1.w + a2.w + a3.w + nv.w + cv.w + xv.w * di;
    *(float4*)(tmp + o) = a0;
}

// ---- Kernel 9: out = tmp @ fW^T + fb  (32 rows/block) ---------------------
__global__ __launch_bounds__(256) void fusion_kernel(
    const float* __restrict__ tmp, const float* __restrict__ fW,
    const float* __restrict__ fb, float* __restrict__ out, int N)
{
    __shared__ float Wt[C][C + 1];   // Wt[k][j] = fW[j*C+k]
    __shared__ float tl[32][C];
    int t = threadIdx.x;
    #pragma unroll
    for (int i = 0; i < 16; ++i) {
        int idx = t + i * 256;
        Wt[idx & 63][idx >> 6] = fW[idx];
    }
    int n0 = blockIdx.x * 32;
    #pragma unroll
    for (int i = 0; i < 2; ++i) {
        int idx = t + i * 256;
        int rr = idx >> 4, cc = (idx & 15) << 2;
        int n = n0 + rr;
        float4 v = (n < N) ? *(const float4*)(tmp + (size_t)n * C + cc)
                           : make_float4(0.f, 0.f, 0.f, 0.f);
        *(float4*)(&tl[rr][cc]) = v;
    }
    __syncthreads();

    int j = t & 63, rb = (t >> 6) * 8;
    float bj = fb[j];
    float acc[8] = {bj, bj, bj, bj, bj, bj, bj, bj};
    for (int k = 0; k < C; ++k) {
        float w = Wt[k][j];
        #pragma unroll
        for (int q = 0; q < 8; ++q) acc[q] = fmaf(tl[rb + q][k], w, acc[q]);
    }
    #pragma unroll
    for (int q = 0; q < 8; ++q) {
        int n = n0 + rb + q;
        if (n < N) out[(size_t)n * C + j] = acc[q];
    }
}

extern "C" void kernel_launch(void* const* d_in, const int* in_sizes, int n_in,
                              void* d_out, int out_size, void* d_ws, size_t ws_size,
                              hipStream_t stream)
{
    const float* X        = (const float*)d_in[0];
    const int*   ei       = (const int*)d_in[1];
    const float* ew       = (const float*)d_in[2];
    const float* node_emb = (const float*)d_in[3];
    const float* com_emb  = (const float*)d_in[4];
    const float* cw       = (const float*)d_in[5];
    const float* w_ih_f   = (const float*)d_in[6];
    const float* b_ih_f   = (const float*)d_in[7];
    const float* b_hh_f   = (const float*)d_in[8];
    const float* w_ih_b   = (const float*)d_in[9];
    const float* b_ih_b   = (const float*)d_in[10];
    const float* b_hh_b   = (const float*)d_in[11];
    const float* fW       = (const float*)d_in[12];
    const float* fb       = (const float*)d_in[13];
    float* out = (float*)d_out;

    const int N = in_sizes[0] / C;
    const int E = in_sizes[2];
    const int* row = ei;               // edge_index[0]
    const int* col = ei + E;           // edge_index[1]
    const int nbuck = (N + BN - 1) / BN;
    const int epb = (E + NPART - 1) / NPART;

    // ---- workspace layout ----
    // [W][dinv][bb][seg][payload2: E*8][tmp: N*C*4]
    // pass-1 payload + hist alias INTO tmp (dead before reduce writes tmp).
    // Xw' lives in d_out until fusion overwrites it (fusion stages its own
    // 32 rows of tmp in LDS first; reduce reads Xw' only).
    char* wsb = (char*)d_ws;
    size_t o = 0;
    auto alloc = [&](size_t bytes) { void* p = wsb + o; o = (o + bytes + 15) & ~(size_t)15; return p; };
    float* W        = (float*)alloc((size_t)C * C * sizeof(float));      // 16 KB
    float* dinv     = (float*)alloc((size_t)N * sizeof(float));          // 400 KB
    int*   bb       = (int*)  alloc((size_t)(nbuck + 1) * sizeof(int));  // 3 KB
    int2*  seg      = (int2*) alloc((size_t)N * sizeof(int2));           // 800 KB
    int2*  payload2 = (int2*) alloc((size_t)E * sizeof(int2));           // 12.8 MB
    float* tmp      = (float*)alloc((size_t)N * C * sizeof(float));      // 25.6 MB
    int2*  payload  = (int2*)tmp;                       // 12.8 MB alias
    int*   hist     = (int*)(tmp + (size_t)E * 2);      // 800 KB alias after payload
    float* Xw       = out;             // d_out holds Xw' until fusion overwrites

    lstm_w_kernel<<<(C * C) / 256, 256, 0, stream>>>(
        cw, w_ih_f, b_ih_f, b_hh_f, w_ih_b, b_ih_b, b_hh_b, W);

    hist_kernel<<<NPART, 256, 0, stream>>>(col, hist, E, nbuck, epb);
    scan_blocks_kernel<<<(nbuck + 255) / 256, 256, 0, stream>>>(hist, bb, nbuck);
    scan_spine_kernel<<<1, 256, 0, stream>>>(bb, nbuck, E);
    partition_kernel<<<NPART, 256, 0, stream>>>(
        row, col, ew, hist, bb, payload, E, nbuck, epb);

    sort_bucket_kernel<<<nbuck, 256, 0, stream>>>(
        payload, bb, payload2, dinv, seg, N);

    gemm_xw_kernel<<<(N + 31) / 32, 256, 0, stream>>>(X, W, dinv, Xw, N);

    reduce_kernel<<<(N * 16 + 255) / 256, 256, 0, stream>>>(
        seg, payload2, Xw, dinv, node_emb, com_emb, tmp, N);

    fusion_kernel<<<(N + 31) / 32, 256, 0, stream>>>(tmp, fW, fb, out, N);
}

// Round 7
// 165.161 us; speedup vs baseline: 2.0002x; 1.3660x over previous
//
#include <hip/hip_runtime.h>
#include <math.h>

#define C 64
#define BN 128              // nodes per destination bucket
#define BSHIFT 7            // log2(BN)
#define NPART 256           // partition blocks
#define RMASK ((1 << 20) - 1)

typedef unsigned int uint;
typedef unsigned short ushort;

__device__ __forceinline__ float sigf(float x) { return 1.0f / (1.0f + __expf(-x)); }

// round-to-nearest-even f32 -> bf16 bits (values are finite, no NaN handling)
__device__ __forceinline__ ushort f2bf(float f) {
    uint u = __float_as_uint(f);
    return (ushort)((u + 0x7fffu + ((u >> 16) & 1u)) >> 16);
}

// unpack 4 packed bf16 (uint2) -> float4
__device__ __forceinline__ float4 bf4(uint2 u) {
    float4 r;
    r.x = __uint_as_float(u.x << 16);
    r.y = __uint_as_float(u.x & 0xffff0000u);
    r.z = __uint_as_float(u.y << 16);
    r.w = __uint_as_float(u.y & 0xffff0000u);
    return r;
}

// ---- Kernel 1: W = max(lstm_fwd(conv_w), lstm_bwd(conv_w)) ----------------
__global__ __launch_bounds__(256) void lstm_w_kernel(
    const float* __restrict__ cw,
    const float* __restrict__ wf, const float* __restrict__ bif, const float* __restrict__ bhf,
    const float* __restrict__ wb, const float* __restrict__ bib, const float* __restrict__ bhb,
    float* __restrict__ W)
{
    int tid = blockIdx.x * blockDim.x + threadIdx.x;   // 0..4095
    int r = tid >> 6, c = tid & 63;
    const float* x = cw + r * C;

    const float* f_i = wf + (0 * C + c) * C;
    const float* f_g = wf + (2 * C + c) * C;
    const float* f_o = wf + (3 * C + c) * C;
    const float* b_i = wb + (0 * C + c) * C;
    const float* b_g = wb + (2 * C + c) * C;
    const float* b_o = wb + (3 * C + c) * C;

    float zif = 0.f, zgf = 0.f, zof = 0.f, zib = 0.f, zgb = 0.f, zob = 0.f;
    #pragma unroll
    for (int k = 0; k < C; ++k) {
        float xv = x[k];
        zif = fmaf(xv, f_i[k], zif);
        zgf = fmaf(xv, f_g[k], zgf);
        zof = fmaf(xv, f_o[k], zof);
        zib = fmaf(xv, b_i[k], zib);
        zgb = fmaf(xv, b_g[k], zgb);
        zob = fmaf(xv, b_o[k], zob);
    }
    zif += bif[0 * C + c] + bhf[0 * C + c];
    zgf += bif[2 * C + c] + bhf[2 * C + c];
    zof += bif[3 * C + c] + bhf[3 * C + c];
    zib += bib[0 * C + c] + bhb[0 * C + c];
    zgb += bib[2 * C + c] + bhb[2 * C + c];
    zob += bib[3 * C + c] + bhb[3 * C + c];

    float cf = sigf(zif) * tanhf(zgf);
    float hf = sigf(zof) * tanhf(cf);
    float cb = sigf(zib) * tanhf(zgb);
    float hb = sigf(zob) * tanhf(cb);
    W[tid] = fmaxf(hf, hb);
}

// ---- Kernel 2: per-block bucket histogram (LDS atomics only) --------------
__global__ __launch_bounds__(256) void hist_kernel(
    const int* __restrict__ col, int* __restrict__ hist,
    int E, int nbuck, int epb)
{
    __shared__ int h[1024];
    int t = threadIdx.x, b = blockIdx.x;
    for (int i = t; i < nbuck; i += 256) h[i] = 0;
    __syncthreads();
    int base = b * epb;
    int end = min(base + epb, E);
    for (int e = base + t; e < end; e += 256)
        atomicAdd(&h[col[e] >> BSHIFT], 1);
    __syncthreads();
    for (int i = t; i < nbuck; i += 256) hist[b * nbuck + i] = h[i];
}

// ---- Kernel 3: per-bucket exclusive scan over blocks (parallel) -----------
// One block per bucket k: 256 threads scan hist[b][k] over b.
__global__ __launch_bounds__(256) void scan_blocks_kernel(
    int* __restrict__ hist, int* __restrict__ bb, int nbuck)
{
    __shared__ int wsum[4];
    int k = blockIdx.x;
    int b = threadIdx.x;
    int v = hist[b * nbuck + k];
    int lane = b & 63, wid = b >> 6;
    int x = v;
    #pragma unroll
    for (int d = 1; d < 64; d <<= 1) {
        int y = __shfl_up(x, d, 64);
        if (lane >= d) x += y;
    }
    if (lane == 63) wsum[wid] = x;
    __syncthreads();
    if (b == 0) {
        int run = 0;
        #pragma unroll
        for (int w = 0; w < 4; ++w) { int z = wsum[w]; wsum[w] = run; run += z; }
    }
    __syncthreads();
    int excl = x - v + wsum[wid];
    hist[b * nbuck + k] = excl;
    if (b == 255) bb[k] = excl + v;
}

// ---- Kernel 4: exclusive scan of bucket totals (single block) -------------
__global__ __launch_bounds__(256) void scan_spine_kernel(
    int* __restrict__ bb, int nbuck, int E)
{
    __shared__ int wsum[4];
    int t = threadIdx.x;
    int base = t * 4;
    int v[4];
    #pragma unroll
    for (int j = 0; j < 4; ++j) {
        int idx = base + j;
        v[j] = (idx < nbuck) ? bb[idx] : 0;
    }
    int tsum = v[0] + v[1] + v[2] + v[3];
    int lane = t & 63, wid = t >> 6;
    int x = tsum;
    #pragma unroll
    for (int d = 1; d < 64; d <<= 1) {
        int y = __shfl_up(x, d, 64);
        if (lane >= d) x += y;
    }
    if (lane == 63) wsum[wid] = x;
    __syncthreads();
    if (t == 0) {
        int run = 0;
        #pragma unroll
        for (int w = 0; w < 4; ++w) { int z = wsum[w]; wsum[w] = run; run += z; }
    }
    __syncthreads();
    int run = x - tsum + wsum[wid];
    #pragma unroll
    for (int j = 0; j < 4; ++j) {
        int idx = base + j;
        if (idx < nbuck) bb[idx] = run;
        run += v[j];
    }
    if (t == 0) bb[nbuck] = E;
}

// ---- Kernel 5: partition — scatter {row|ld<<20, w} into bucket ranges -----
__global__ __launch_bounds__(256) void partition_kernel(
    const int* __restrict__ row, const int* __restrict__ col,
    const float* __restrict__ ew, const int* __restrict__ hist,
    const int* __restrict__ bb, int2* __restrict__ payload,
    int E, int nbuck, int epb)
{
    __shared__ int cur[1024];
    int t = threadIdx.x, b = blockIdx.x;
    for (int i = t; i < nbuck; i += 256)
        cur[i] = hist[b * nbuck + i] + bb[i];
    __syncthreads();
    int base = b * epb;
    int end = min(base + epb, E);
    for (int e = base + t; e < end; e += 256) {
        int c = col[e];
        int k = c >> BSHIFT;
        int pos = atomicAdd(&cur[k], 1);
        payload[pos] = make_int2(row[e] | ((c & (BN - 1)) << 20),
                                 __float_as_int(ew[e]));
    }
}

// ---- Kernel 6: per-bucket counting sort by node + deg/dinv + fold dinv[dst]
__global__ __launch_bounds__(256) void sort_bucket_kernel(
    const int2* __restrict__ payload, const int* __restrict__ bb,
    int2* __restrict__ payload2, float* __restrict__ dinv,
    int2* __restrict__ seg, int N)
{
    __shared__ int bin[BN];
    __shared__ int bbase[BN];
    __shared__ int cur[BN];
    __shared__ float degl[BN];
    __shared__ float dinvl[BN];
    int t = threadIdx.x, k = blockIdx.x;
    if (t < BN) { bin[t] = 0; degl[t] = 0.f; }
    __syncthreads();

    int e0 = bb[k], e1 = bb[k + 1];
    for (int e = e0 + t; e < e1; e += 256) {
        int2 p = payload[e];
        int ld = p.x >> 20;
        atomicAdd(&bin[ld], 1);
        atomicAdd(&degl[ld], __int_as_float(p.y));
    }
    __syncthreads();

    // exclusive scan of bin[0..127] in wave 0 (2 bins per lane)
    if (t < 64) {
        int a = bin[2 * t], b2 = bin[2 * t + 1];
        int s = a + b2;
        int x = s;
        #pragma unroll
        for (int d = 1; d < 64; d <<= 1) {
            int y = __shfl_up(x, d, 64);
            if (t >= d) x += y;
        }
        int excl = x - s;
        bbase[2 * t] = excl;
        bbase[2 * t + 1] = excl + a;
    }
    __syncthreads();

    if (t < BN) {
        int n = k * BN + t;
        float di = rsqrtf(degl[t] + 1.0f);    // +1 self-loop weight
        dinvl[t] = di;
        cur[t] = e0 + bbase[t];
        if (n < N) {
            dinv[n] = di;
            seg[n] = make_int2(e0 + bbase[t], bin[t]);
        }
    }
    __syncthreads();

    for (int e = e0 + t; e < e1; e += 256) {
        int2 p = payload[e];
        int ld = p.x >> 20;
        int pos = atomicAdd(&cur[ld], 1);
        payload2[pos] = make_int2(p.x & RMASK,
                                  __float_as_int(__int_as_float(p.y) * dinvl[ld]));
    }
}

// ---- Kernel 7: Xw' = bf16( dinv ⊙ (X @ W) )  (row-scaled, 32 rows/block) --
__global__ __launch_bounds__(256) void gemm_xw_kernel(
    const float* __restrict__ X, const float* __restrict__ W,
    const float* __restrict__ dinv, ushort* __restrict__ Y, int N)
{
    __shared__ float Wl[C * C];
    __shared__ float xl[32][C];
    int t = threadIdx.x;
    #pragma unroll
    for (int i = 0; i < 4; ++i)
        *(float4*)(Wl + 4 * (t + i * 256)) = *(const float4*)(W + 4 * (t + i * 256));

    int n0 = blockIdx.x * 32;
    #pragma unroll
    for (int i = 0; i < 2; ++i) {
        int idx = t + i * 256;            // 0..511 : (row, float4-group)
        int rr = idx >> 4, cc = (idx & 15) << 2;
        int n = n0 + rr;
        float4 v = (n < N) ? *(const float4*)(X + (size_t)n * C + cc)
                           : make_float4(0.f, 0.f, 0.f, 0.f);
        *(float4*)(&xl[rr][cc]) = v;
    }
    __syncthreads();

    int c = t & 63, rb = (t >> 6) * 8;
    float acc[8] = {0.f, 0.f, 0.f, 0.f, 0.f, 0.f, 0.f, 0.f};
    for (int k = 0; k < C; ++k) {
        float w = Wl[k * C + c];
        #pragma unroll
        for (int q = 0; q < 8; ++q) acc[q] = fmaf(xl[rb + q][k], w, acc[q]);
    }
    #pragma unroll
    for (int q = 0; q < 8; ++q) {
        int n = n0 + rb + q;
        if (n < N) Y[(size_t)n * C + c] = f2bf(acc[q] * dinv[n]);  // fold dinv[src]
    }
}

// ---- Kernel 8: gather-reduce, 16 lanes/node, 4-wide ILP, bf16 gathers -----
// tmp[n] = ne + ce + dinv[n]*Xw'[n] + sum_seg pn * Xw'[src]
__global__ __launch_bounds__(256) void reduce_kernel(
    const int2* __restrict__ seg, const int2* __restrict__ payload2,
    const ushort* __restrict__ Xw, const float* __restrict__ dinv,
    const float* __restrict__ ne, const float* __restrict__ ce,
    float* __restrict__ tmp, int N)
{
    int t = blockIdx.x * 256 + threadIdx.x;
    int n = t >> 4;
    if (n >= N) return;
    int cg = (t & 15) << 2;

    int2 s = seg[n];
    int p = s.x, cnt = s.y;
    float4 a0 = make_float4(0.f, 0.f, 0.f, 0.f);
    float4 a1 = a0, a2 = a0, a3 = a0;
    while (cnt >= 4) {
        int2 p0 = payload2[p];
        int2 p1 = payload2[p + 1];
        int2 p2 = payload2[p + 2];
        int2 p3 = payload2[p + 3];
        uint2 u0 = *(const uint2*)(Xw + (size_t)p0.x * C + cg);
        uint2 u1 = *(const uint2*)(Xw + (size_t)p1.x * C + cg);
        uint2 u2 = *(const uint2*)(Xw + (size_t)p2.x * C + cg);
        uint2 u3 = *(const uint2*)(Xw + (size_t)p3.x * C + cg);
        float4 v0 = bf4(u0), v1 = bf4(u1), v2 = bf4(u2), v3 = bf4(u3);
        float n0 = __int_as_float(p0.y), n1 = __int_as_float(p1.y);
        float n2 = __int_as_float(p2.y), n3 = __int_as_float(p3.y);
        a0.x = fmaf(v0.x, n0, a0.x); a0.y = fmaf(v0.y, n0, a0.y);
        a0.z = fmaf(v0.z, n0, a0.z); a0.w = fmaf(v0.w, n0, a0.w);
        a1.x = fmaf(v1.x, n1, a1.x); a1.y = fmaf(v1.y, n1, a1.y);
        a1.z = fmaf(v1.z, n1, a1.z); a1.w = fmaf(v1.w, n1, a1.w);
        a2.x = fmaf(v2.x, n2, a2.x); a2.y = fmaf(v2.y, n2, a2.y);
        a2.z = fmaf(v2.z, n2, a2.z); a2.w = fmaf(v2.w, n2, a2.w);
        a3.x = fmaf(v3.x, n3, a3.x); a3.y = fmaf(v3.y, n3, a3.y);
        a3.z = fmaf(v3.z, n3, a3.z); a3.w = fmaf(v3.w, n3, a3.w);
        p += 4; cnt -= 4;
    }
    while (cnt > 0) {
        int2 pl = payload2[p];
        float nn = __int_as_float(pl.y);
        float4 v = bf4(*(const uint2*)(Xw + (size_t)pl.x * C + cg));
        a0.x = fmaf(v.x, nn, a0.x); a0.y = fmaf(v.y, nn, a0.y);
        a0.z = fmaf(v.z, nn, a0.z); a0.w = fmaf(v.w, nn, a0.w);
        ++p; --cnt;
    }
    float di = dinv[n];
    size_t o = (size_t)n * C + cg;
    float4 xv = bf4(*(const uint2*)(Xw + o));   // Xw' = dinv[n]*(X@W)[n]
    const float4 nv = *(const float4*)(ne + o);
    const float4 cv = *(const float4*)(ce + o);
    a0.x += a1.x + a2.x + a3.x + nv.x + cv.x + xv.x * di;
    a0.y += a1.y + a2.y + a3.y + nv.y + cv.y + xv.y * di;
    a0.z += a1.z + a2.z + a3.z + nv.z + cv.z + xv.z * di;
    a0.w += a1.w + a2.w + a3.w + nv.w + cv.w + xv.w * di;
    *(float4*)(tmp + o) = a0;
}

// ---- Kernel 9: out = tmp @ fW^T + fb  (32 rows/block) ---------------------
__global__ __launch_bounds__(256) void fusion_kernel(
    const float* __restrict__ tmp, const float* __restrict__ fW,
    const float* __restrict__ fb, float* __restrict__ out, int N)
{
    __shared__ float Wt[C][C + 1];   // Wt[k][j] = fW[j*C+k]
    __shared__ float tl[32][C];
    int t = threadIdx.x;
    #pragma unroll
    for (int i = 0; i < 16; ++i) {
        int idx = t + i * 256;
        Wt[idx & 63][idx >> 6] = fW[idx];
    }
    int n0 = blockIdx.x * 32;
    #pragma unroll
    for (int i = 0; i < 2; ++i) {
        int idx = t + i * 256;
        int rr = idx >> 4, cc = (idx & 15) << 2;
        int n = n0 + rr;
        float4 v = (n < N) ? *(const float4*)(tmp + (size_t)n * C + cc)
                           : make_float4(0.f, 0.f, 0.f, 0.f);
        *(float4*)(&tl[rr][cc]) = v;
    }
    __syncthreads();

    int j = t & 63, rb = (t >> 6) * 8;
    float bj = fb[j];
    float acc[8] = {bj, bj, bj, bj, bj, bj, bj, bj};
    for (int k = 0; k < C; ++k) {
        float w = Wt[k][j];
        #pragma unroll
        for (int q = 0; q < 8; ++q) acc[q] = fmaf(tl[rb + q][k], w, acc[q]);
    }
    #pragma unroll
    for (int q = 0; q < 8; ++q) {
        int n = n0 + rb + q;
        if (n < N) out[(size_t)n * C + j] = acc[q];
    }
}

extern "C" void kernel_launch(void* const* d_in, const int* in_sizes, int n_in,
                              void* d_out, int out_size, void* d_ws, size_t ws_size,
                              hipStream_t stream)
{
    const float* X        = (const float*)d_in[0];
    const int*   ei       = (const int*)d_in[1];
    const float* ew       = (const float*)d_in[2];
    const float* node_emb = (const float*)d_in[3];
    const float* com_emb  = (const float*)d_in[4];
    const float* cw       = (const float*)d_in[5];
    const float* w_ih_f   = (const float*)d_in[6];
    const float* b_ih_f   = (const float*)d_in[7];
    const float* b_hh_f   = (const float*)d_in[8];
    const float* w_ih_b   = (const float*)d_in[9];
    const float* b_ih_b   = (const float*)d_in[10];
    const float* b_hh_b   = (const float*)d_in[11];
    const float* fW       = (const float*)d_in[12];
    const float* fb       = (const float*)d_in[13];
    float* out = (float*)d_out;

    const int N = in_sizes[0] / C;
    const int E = in_sizes[2];
    const int* row = ei;               // edge_index[0]
    const int* col = ei + E;           // edge_index[1]
    const int nbuck = (N + BN - 1) / BN;
    const int epb = (E + NPART - 1) / NPART;

    // ---- workspace layout ----
    // [W][dinv][bb][seg][payload2: E*8][tmp: N*C*4]
    // pass-1 payload + hist alias INTO tmp (dead before reduce writes tmp).
    // Xw' (bf16, N*C*2 = 12.8MB) lives in d_out until fusion overwrites it.
    char* wsb = (char*)d_ws;
    size_t o = 0;
    auto alloc = [&](size_t bytes) { void* p = wsb + o; o = (o + bytes + 15) & ~(size_t)15; return p; };
    float* W        = (float*)alloc((size_t)C * C * sizeof(float));      // 16 KB
    float* dinv     = (float*)alloc((size_t)N * sizeof(float));          // 400 KB
    int*   bb       = (int*)  alloc((size_t)(nbuck + 1) * sizeof(int));  // 3 KB
    int2*  seg      = (int2*) alloc((size_t)N * sizeof(int2));           // 800 KB
    int2*  payload2 = (int2*) alloc((size_t)E * sizeof(int2));           // 12.8 MB
    float* tmp      = (float*)alloc((size_t)N * C * sizeof(float));      // 25.6 MB
    int2*  payload  = (int2*)tmp;                       // 12.8 MB alias
    int*   hist     = (int*)(tmp + (size_t)E * 2);      // 800 KB alias after payload
    ushort* Xw      = (ushort*)out;    // d_out holds bf16 Xw' until fusion overwrites

    lstm_w_kernel<<<(C * C) / 256, 256, 0, stream>>>(
        cw, w_ih_f, b_ih_f, b_hh_f, w_ih_b, b_ih_b, b_hh_b, W);

    hist_kernel<<<NPART, 256, 0, stream>>>(col, hist, E, nbuck, epb);
    scan_blocks_kernel<<<nbuck, 256, 0, stream>>>(hist, bb, nbuck);
    scan_spine_kernel<<<1, 256, 0, stream>>>(bb, nbuck, E);
    partition_kernel<<<NPART, 256, 0, stream>>>(
        row, col, ew, hist, bb, payload, E, nbuck, epb);

    sort_bucket_kernel<<<nbuck, 256, 0, stream>>>(
        payload, bb, payload2, dinv, seg, N);

    gemm_xw_kernel<<<(N + 31) / 32, 256, 0, stream>>>(X, W, dinv, Xw, N);

    reduce_kernel<<<(N * 16 + 255) / 256, 256, 0, stream>>>(
        seg, payload2, Xw, dinv, node_emb, com_emb, tmp, N);

    fusion_kernel<<<(N + 31) / 32, 256, 0, stream>>>(tmp, fW, fb, out, N);
}

// Round 8
// 161.038 us; speedup vs baseline: 2.0514x; 1.0256x over previous
//
#include <hip/hip_runtime.h>
#include <math.h>

#define C 64
#define BN 128              // nodes per destination bucket
#define BSHIFT 7            // log2(BN)
#define NPART 512           // partition blocks
#define RMASK ((1 << 20) - 1)

typedef unsigned int uint;
typedef unsigned short ushort;

__device__ __forceinline__ float sigf(float x) { return 1.0f / (1.0f + __expf(-x)); }

// round-to-nearest-even f32 -> bf16 bits (values are finite, no NaN handling)
__device__ __forceinline__ ushort f2bf(float f) {
    uint u = __float_as_uint(f);
    return (ushort)((u + 0x7fffu + ((u >> 16) & 1u)) >> 16);
}

// fma 8 packed bf16 (uint4) into acc[8]
__device__ __forceinline__ void bf8fma(uint4 u, float nn, float* a) {
    a[0] = fmaf(__uint_as_float(u.x << 16),          nn, a[0]);
    a[1] = fmaf(__uint_as_float(u.x & 0xffff0000u),  nn, a[1]);
    a[2] = fmaf(__uint_as_float(u.y << 16),          nn, a[2]);
    a[3] = fmaf(__uint_as_float(u.y & 0xffff0000u),  nn, a[3]);
    a[4] = fmaf(__uint_as_float(u.z << 16),          nn, a[4]);
    a[5] = fmaf(__uint_as_float(u.z & 0xffff0000u),  nn, a[5]);
    a[6] = fmaf(__uint_as_float(u.w << 16),          nn, a[6]);
    a[7] = fmaf(__uint_as_float(u.w & 0xffff0000u),  nn, a[7]);
}

// ---- Kernel 1: W = max(lstm_fwd(conv_w), lstm_bwd(conv_w)) ----------------
__global__ __launch_bounds__(256) void lstm_w_kernel(
    const float* __restrict__ cw,
    const float* __restrict__ wf, const float* __restrict__ bif, const float* __restrict__ bhf,
    const float* __restrict__ wb, const float* __restrict__ bib, const float* __restrict__ bhb,
    float* __restrict__ W)
{
    int tid = blockIdx.x * blockDim.x + threadIdx.x;   // 0..4095
    int r = tid >> 6, c = tid & 63;
    const float* x = cw + r * C;

    const float* f_i = wf + (0 * C + c) * C;
    const float* f_g = wf + (2 * C + c) * C;
    const float* f_o = wf + (3 * C + c) * C;
    const float* b_i = wb + (0 * C + c) * C;
    const float* b_g = wb + (2 * C + c) * C;
    const float* b_o = wb + (3 * C + c) * C;

    float zif = 0.f, zgf = 0.f, zof = 0.f, zib = 0.f, zgb = 0.f, zob = 0.f;
    #pragma unroll
    for (int k = 0; k < C; ++k) {
        float xv = x[k];
        zif = fmaf(xv, f_i[k], zif);
        zgf = fmaf(xv, f_g[k], zgf);
        zof = fmaf(xv, f_o[k], zof);
        zib = fmaf(xv, b_i[k], zib);
        zgb = fmaf(xv, b_g[k], zgb);
        zob = fmaf(xv, b_o[k], zob);
    }
    zif += bif[0 * C + c] + bhf[0 * C + c];
    zgf += bif[2 * C + c] + bhf[2 * C + c];
    zof += bif[3 * C + c] + bhf[3 * C + c];
    zib += bib[0 * C + c] + bhb[0 * C + c];
    zgb += bib[2 * C + c] + bhb[2 * C + c];
    zob += bib[3 * C + c] + bhb[3 * C + c];

    float cf = sigf(zif) * tanhf(zgf);
    float hf = sigf(zof) * tanhf(cf);
    float cb = sigf(zib) * tanhf(zgb);
    float hb = sigf(zob) * tanhf(cb);
    W[tid] = fmaxf(hf, hb);
}

// ---- Kernel 2: per-block bucket histogram (LDS atomics only) --------------
__global__ __launch_bounds__(256) void hist_kernel(
    const int* __restrict__ col, int* __restrict__ hist,
    int E, int nbuck, int epb)
{
    __shared__ int h[1024];
    int t = threadIdx.x, b = blockIdx.x;
    for (int i = t; i < nbuck; i += 256) h[i] = 0;
    __syncthreads();
    int base = b * epb;
    int end = min(base + epb, E);
    for (int e = base + t; e < end; e += 256)
        atomicAdd(&h[col[e] >> BSHIFT], 1);
    __syncthreads();
    for (int i = t; i < nbuck; i += 256) hist[b * nbuck + i] = h[i];
}

// ---- Kernel 3: per-bucket exclusive scan over blocks (parallel) -----------
// One block per bucket k: NPART threads scan hist[b][k] over b.
__global__ __launch_bounds__(512) void scan_blocks_kernel(
    int* __restrict__ hist, int* __restrict__ bb, int nbuck)
{
    __shared__ int wsum[8];
    int k = blockIdx.x;
    int b = threadIdx.x;
    int v = hist[b * nbuck + k];
    int lane = b & 63, wid = b >> 6;
    int x = v;
    #pragma unroll
    for (int d = 1; d < 64; d <<= 1) {
        int y = __shfl_up(x, d, 64);
        if (lane >= d) x += y;
    }
    if (lane == 63) wsum[wid] = x;
    __syncthreads();
    if (b == 0) {
        int run = 0;
        #pragma unroll
        for (int w = 0; w < 8; ++w) { int z = wsum[w]; wsum[w] = run; run += z; }
    }
    __syncthreads();
    int excl = x - v + wsum[wid];
    hist[b * nbuck + k] = excl;
    if (b == NPART - 1) bb[k] = excl + v;
}

// ---- Kernel 4: exclusive scan of bucket totals (single block) -------------
__global__ __launch_bounds__(256) void scan_spine_kernel(
    int* __restrict__ bb, int nbuck, int E)
{
    __shared__ int wsum[4];
    int t = threadIdx.x;
    int base = t * 4;
    int v[4];
    #pragma unroll
    for (int j = 0; j < 4; ++j) {
        int idx = base + j;
        v[j] = (idx < nbuck) ? bb[idx] : 0;
    }
    int tsum = v[0] + v[1] + v[2] + v[3];
    int lane = t & 63, wid = t >> 6;
    int x = tsum;
    #pragma unroll
    for (int d = 1; d < 64; d <<= 1) {
        int y = __shfl_up(x, d, 64);
        if (lane >= d) x += y;
    }
    if (lane == 63) wsum[wid] = x;
    __syncthreads();
    if (t == 0) {
        int run = 0;
        #pragma unroll
        for (int w = 0; w < 4; ++w) { int z = wsum[w]; wsum[w] = run; run += z; }
    }
    __syncthreads();
    int run = x - tsum + wsum[wid];
    #pragma unroll
    for (int j = 0; j < 4; ++j) {
        int idx = base + j;
        if (idx < nbuck) bb[idx] = run;
        run += v[j];
    }
    if (t == 0) bb[nbuck] = E;
}

// ---- Kernel 5: partition — scatter {row|ld<<20, w} into bucket ranges -----
__global__ __launch_bounds__(256) void partition_kernel(
    const int* __restrict__ row, const int* __restrict__ col,
    const float* __restrict__ ew, const int* __restrict__ hist,
    const int* __restrict__ bb, int2* __restrict__ payload,
    int E, int nbuck, int epb)
{
    __shared__ int cur[1024];
    int t = threadIdx.x, b = blockIdx.x;
    for (int i = t; i < nbuck; i += 256)
        cur[i] = hist[b * nbuck + i] + bb[i];
    __syncthreads();
    int base = b * epb;
    int end = min(base + epb, E);
    for (int e = base + t; e < end; e += 256) {
        int c = col[e];
        int k = c >> BSHIFT;
        int pos = atomicAdd(&cur[k], 1);
        payload[pos] = make_int2(row[e] | ((c & (BN - 1)) << 20),
                                 __float_as_int(ew[e]));
    }
}

// ---- Kernel 6: per-bucket counting sort by node + deg/dinv + fold dinv[dst]
__global__ __launch_bounds__(512) void sort_bucket_kernel(
    const int2* __restrict__ payload, const int* __restrict__ bb,
    int2* __restrict__ payload2, float* __restrict__ dinv,
    int2* __restrict__ seg, int N)
{
    __shared__ int bin[BN];
    __shared__ int bbase[BN];
    __shared__ int cur[BN];
    __shared__ float degl[BN];
    __shared__ float dinvl[BN];
    int t = threadIdx.x, k = blockIdx.x;
    if (t < BN) { bin[t] = 0; degl[t] = 0.f; }
    __syncthreads();

    int e0 = bb[k], e1 = bb[k + 1];
    for (int e = e0 + t; e < e1; e += 512) {
        int2 p = payload[e];
        int ld = p.x >> 20;
        atomicAdd(&bin[ld], 1);
        atomicAdd(&degl[ld], __int_as_float(p.y));
    }
    __syncthreads();

    // exclusive scan of bin[0..127] in wave 0 (2 bins per lane)
    if (t < 64) {
        int a = bin[2 * t], b2 = bin[2 * t + 1];
        int s = a + b2;
        int x = s;
        #pragma unroll
        for (int d = 1; d < 64; d <<= 1) {
            int y = __shfl_up(x, d, 64);
            if (t >= d) x += y;
        }
        int excl = x - s;
        bbase[2 * t] = excl;
        bbase[2 * t + 1] = excl + a;
    }
    __syncthreads();

    if (t < BN) {
        int n = k * BN + t;
        float di = rsqrtf(degl[t] + 1.0f);    // +1 self-loop weight
        dinvl[t] = di;
        cur[t] = e0 + bbase[t];
        if (n < N) {
            dinv[n] = di;
            seg[n] = make_int2(e0 + bbase[t], bin[t]);
        }
    }
    __syncthreads();

    for (int e = e0 + t; e < e1; e += 512) {
        int2 p = payload[e];
        int ld = p.x >> 20;
        int pos = atomicAdd(&cur[ld], 1);
        payload2[pos] = make_int2(p.x & RMASK,
                                  __float_as_int(__int_as_float(p.y) * dinvl[ld]));
    }
}

// ---- Kernel 7: Xw' = bf16( dinv ⊙ (X @ W) )  (row-scaled, 32 rows/block) --
__global__ __launch_bounds__(256) void gemm_xw_kernel(
    const float* __restrict__ X, const float* __restrict__ W,
    const float* __restrict__ dinv, ushort* __restrict__ Y, int N)
{
    __shared__ float Wl[C * C];
    __shared__ float xl[32][C];
    int t = threadIdx.x;
    #pragma unroll
    for (int i = 0; i < 4; ++i)
        *(float4*)(Wl + 4 * (t + i * 256)) = *(const float4*)(W + 4 * (t + i * 256));

    int n0 = blockIdx.x * 32;
    #pragma unroll
    for (int i = 0; i < 2; ++i) {
        int idx = t + i * 256;            // 0..511 : (row, float4-group)
        int rr = idx >> 4, cc = (idx & 15) << 2;
        int n = n0 + rr;
        float4 v = (n < N) ? *(const float4*)(X + (size_t)n * C + cc)
                           : make_float4(0.f, 0.f, 0.f, 0.f);
        *(float4*)(&xl[rr][cc]) = v;
    }
    __syncthreads();

    int c = t & 63, rb = (t >> 6) * 8;
    float acc[8] = {0.f, 0.f, 0.f, 0.f, 0.f, 0.f, 0.f, 0.f};
    for (int k = 0; k < C; ++k) {
        float w = Wl[k * C + c];
        #pragma unroll
        for (int q = 0; q < 8; ++q) acc[q] = fmaf(xl[rb + q][k], w, acc[q]);
    }
    #pragma unroll
    for (int q = 0; q < 8; ++q) {
        int n = n0 + rb + q;
        if (n < N) Y[(size_t)n * C + c] = f2bf(acc[q] * dinv[n]);  // fold dinv[src]
    }
}

// ---- Kernel 8: gather-reduce, 8 lanes/node, uint4 gathers, 4 edges in flight
// tmp[n] = bf16( ne + ce + dinv[n]*Xw'[n] + sum_seg pn * Xw'[src] )
__global__ __launch_bounds__(256) void reduce_kernel(
    const int2* __restrict__ seg, const int2* __restrict__ payload2,
    const ushort* __restrict__ Xw, const float* __restrict__ dinv,
    const float* __restrict__ ne, const float* __restrict__ ce,
    ushort* __restrict__ tmpb, int N)
{
    int t = blockIdx.x * 256 + threadIdx.x;
    int n = t >> 3;
    if (n >= N) return;
    int cs = (t & 7) << 3;                 // channel offset (8 channels/lane)

    int2 s = seg[n];
    int p = s.x, cnt = s.y;
    float a[8] = {0.f, 0.f, 0.f, 0.f, 0.f, 0.f, 0.f, 0.f};
    while (cnt >= 4) {
        int2 p0 = payload2[p];
        int2 p1 = payload2[p + 1];
        int2 p2 = payload2[p + 2];
        int2 p3 = payload2[p + 3];
        uint4 u0 = *(const uint4*)(Xw + (size_t)p0.x * C + cs);
        uint4 u1 = *(const uint4*)(Xw + (size_t)p1.x * C + cs);
        uint4 u2 = *(const uint4*)(Xw + (size_t)p2.x * C + cs);
        uint4 u3 = *(const uint4*)(Xw + (size_t)p3.x * C + cs);
        bf8fma(u0, __int_as_float(p0.y), a);
        bf8fma(u1, __int_as_float(p1.y), a);
        bf8fma(u2, __int_as_float(p2.y), a);
        bf8fma(u3, __int_as_float(p3.y), a);
        p += 4; cnt -= 4;
    }
    while (cnt > 0) {
        int2 pl = payload2[p];
        uint4 u = *(const uint4*)(Xw + (size_t)pl.x * C + cs);
        bf8fma(u, __int_as_float(pl.y), a);
        ++p; --cnt;
    }
    float di = dinv[n];
    size_t o = (size_t)n * C + cs;
    uint4 ux = *(const uint4*)(Xw + o);     // Xw' = dinv[n]*(X@W)[n]
    bf8fma(ux, di, a);
    const float4 nv0 = *(const float4*)(ne + o);
    const float4 nv1 = *(const float4*)(ne + o + 4);
    const float4 cv0 = *(const float4*)(ce + o);
    const float4 cv1 = *(const float4*)(ce + o + 4);
    a[0] += nv0.x + cv0.x;  a[1] += nv0.y + cv0.y;
    a[2] += nv0.z + cv0.z;  a[3] += nv0.w + cv0.w;
    a[4] += nv1.x + cv1.x;  a[5] += nv1.y + cv1.y;
    a[6] += nv1.z + cv1.z;  a[7] += nv1.w + cv1.w;

    uint4 w;
    w.x = (uint)f2bf(a[0]) | ((uint)f2bf(a[1]) << 16);
    w.y = (uint)f2bf(a[2]) | ((uint)f2bf(a[3]) << 16);
    w.z = (uint)f2bf(a[4]) | ((uint)f2bf(a[5]) << 16);
    w.w = (uint)f2bf(a[6]) | ((uint)f2bf(a[7]) << 16);
    *(uint4*)(tmpb + o) = w;
}

// ---- Kernel 9: out = tmp @ fW^T + fb  (32 rows/block, bf16 tmp input) -----
__global__ __launch_bounds__(256) void fusion_kernel(
    const ushort* __restrict__ tmpb, const float* __restrict__ fW,
    const float* __restrict__ fb, float* __restrict__ out, int N)
{
    __shared__ float Wt[C][C + 1];   // Wt[k][j] = fW[j*C+k]
    __shared__ float tl[32][C];
    int t = threadIdx.x;
    #pragma unroll
    for (int i = 0; i < 16; ++i) {
        int idx = t + i * 256;
        Wt[idx & 63][idx >> 6] = fW[idx];
    }
    int n0 = blockIdx.x * 32;
    {
        int rr = t >> 3, cs = (t & 7) << 3;
        int n = n0 + rr;
        uint4 u = (n < N) ? *(const uint4*)(tmpb + (size_t)n * C + cs)
                          : make_uint4(0u, 0u, 0u, 0u);
        tl[rr][cs + 0] = __uint_as_float(u.x << 16);
        tl[rr][cs + 1] = __uint_as_float(u.x & 0xffff0000u);
        tl[rr][cs + 2] = __uint_as_float(u.y << 16);
        tl[rr][cs + 3] = __uint_as_float(u.y & 0xffff0000u);
        tl[rr][cs + 4] = __uint_as_float(u.z << 16);
        tl[rr][cs + 5] = __uint_as_float(u.z & 0xffff0000u);
        tl[rr][cs + 6] = __uint_as_float(u.w << 16);
        tl[rr][cs + 7] = __uint_as_float(u.w & 0xffff0000u);
    }
    __syncthreads();

    int j = t & 63, rb = (t >> 6) * 8;
    float bj = fb[j];
    float acc[8] = {bj, bj, bj, bj, bj, bj, bj, bj};
    for (int k = 0; k < C; ++k) {
        float w = Wt[k][j];
        #pragma unroll
        for (int q = 0; q < 8; ++q) acc[q] = fmaf(tl[rb + q][k], w, acc[q]);
    }
    #pragma unroll
    for (int q = 0; q < 8; ++q) {
        int n = n0 + rb + q;
        if (n < N) out[(size_t)n * C + j] = acc[q];
    }
}

extern "C" void kernel_launch(void* const* d_in, const int* in_sizes, int n_in,
                              void* d_out, int out_size, void* d_ws, size_t ws_size,
                              hipStream_t stream)
{
    const float* X        = (const float*)d_in[0];
    const int*   ei       = (const int*)d_in[1];
    const float* ew       = (const float*)d_in[2];
    const float* node_emb = (const float*)d_in[3];
    const float* com_emb  = (const float*)d_in[4];
    const float* cw       = (const float*)d_in[5];
    const float* w_ih_f   = (const float*)d_in[6];
    const float* b_ih_f   = (const float*)d_in[7];
    const float* b_hh_f   = (const float*)d_in[8];
    const float* w_ih_b   = (const float*)d_in[9];
    const float* b_ih_b   = (const float*)d_in[10];
    const float* b_hh_b   = (const float*)d_in[11];
    const float* fW       = (const float*)d_in[12];
    const float* fb       = (const float*)d_in[13];
    float* out = (float*)d_out;

    const int N = in_sizes[0] / C;
    const int E = in_sizes[2];
    const int* row = ei;               // edge_index[0]
    const int* col = ei + E;           // edge_index[1]
    const int nbuck = (N + BN - 1) / BN;
    const int epb = (E + NPART - 1) / NPART;

    // ---- workspace layout ----
    // [W][dinv][bb][seg][payload2: E*8][big: max(E*8 + hist, N*C*2)]
    // pass-1 payload + hist alias INTO big (dead before reduce writes tmpb).
    // Xw' (bf16) lives in d_out until fusion overwrites it.
    char* wsb = (char*)d_ws;
    size_t o = 0;
    auto alloc = [&](size_t bytes) { void* p = wsb + o; o = (o + bytes + 15) & ~(size_t)15; return p; };
    float* W        = (float*)alloc((size_t)C * C * sizeof(float));      // 16 KB
    float* dinv     = (float*)alloc((size_t)N * sizeof(float));          // 400 KB
    int*   bb       = (int*)  alloc((size_t)(nbuck + 1) * sizeof(int));  // 3 KB
    int2*  seg      = (int2*) alloc((size_t)N * sizeof(int2));           // 800 KB
    int2*  payload2 = (int2*) alloc((size_t)E * sizeof(int2));           // 12.8 MB
    size_t big_bytes_a = (size_t)E * 8 + (size_t)NPART * nbuck * 4;      // payload+hist
    size_t big_bytes_b = (size_t)N * C * 2;                              // tmpb
    char*  big      = (char*)alloc(big_bytes_a > big_bytes_b ? big_bytes_a : big_bytes_b);
    int2*  payload  = (int2*)big;
    int*   hist     = (int*)(big + (size_t)E * 8);
    ushort* tmpb    = (ushort*)big;
    ushort* Xw      = (ushort*)out;    // d_out holds bf16 Xw' until fusion overwrites

    lstm_w_kernel<<<(C * C) / 256, 256, 0, stream>>>(
        cw, w_ih_f, b_ih_f, b_hh_f, w_ih_b, b_ih_b, b_hh_b, W);

    hist_kernel<<<NPART, 256, 0, stream>>>(col, hist, E, nbuck, epb);
    scan_blocks_kernel<<<nbuck, 512, 0, stream>>>(hist, bb, nbuck);
    scan_spine_kernel<<<1, 256, 0, stream>>>(bb, nbuck, E);
    partition_kernel<<<NPART, 256, 0, stream>>>(
        row, col, ew, hist, bb, payload, E, nbuck, epb);

    sort_bucket_kernel<<<nbuck, 512, 0, stream>>>(
        payload, bb, payload2, dinv, seg, N);

    gemm_xw_kernel<<<(N + 31) / 32, 256, 0, stream>>>(X, W, dinv, Xw, N);

    reduce_kernel<<<(N * 8 + 255) / 256, 256, 0, stream>>>(
        seg, payload2, Xw, dinv, node_emb, com_emb, tmpb, N);

    fusion_kernel<<<(N + 31) / 32, 256, 0, stream>>>(tmpb, fW, fb, out, N);
}

// Round 9
// 152.448 us; speedup vs baseline: 2.1670x; 1.0563x over previous
//
#include <hip/hip_runtime.h>
#include <math.h>

#define C 64
#define BN 128              // nodes per destination bucket
#define BSHIFT 7            // log2(BN)
#define NPART 512           // partition blocks
#define EPB_CAP 3200        // LDS staging capacity per partition block
#define SCAP 4096           // LDS staging capacity per sort bucket (mean 2046, 45 sigma)
#define RMASK ((1 << 20) - 1)

typedef unsigned int uint;
typedef unsigned short ushort;

__device__ __forceinline__ float sigf(float x) { return 1.0f / (1.0f + __expf(-x)); }

// round-to-nearest-even f32 -> bf16 bits (values are finite, no NaN handling)
__device__ __forceinline__ ushort f2bf(float f) {
    uint u = __float_as_uint(f);
    return (ushort)((u + 0x7fffu + ((u >> 16) & 1u)) >> 16);
}

// fma 8 packed bf16 (uint4) into acc[8]
__device__ __forceinline__ void bf8fma(uint4 u, float nn, float* a) {
    a[0] = fmaf(__uint_as_float(u.x << 16),          nn, a[0]);
    a[1] = fmaf(__uint_as_float(u.x & 0xffff0000u),  nn, a[1]);
    a[2] = fmaf(__uint_as_float(u.y << 16),          nn, a[2]);
    a[3] = fmaf(__uint_as_float(u.y & 0xffff0000u),  nn, a[3]);
    a[4] = fmaf(__uint_as_float(u.z << 16),          nn, a[4]);
    a[5] = fmaf(__uint_as_float(u.z & 0xffff0000u),  nn, a[5]);
    a[6] = fmaf(__uint_as_float(u.w << 16),          nn, a[6]);
    a[7] = fmaf(__uint_as_float(u.w & 0xffff0000u),  nn, a[7]);
}

// ---- Kernel 1: W = max(lstm_fwd(conv_w), lstm_bwd(conv_w)) ----------------
__global__ __launch_bounds__(256) void lstm_w_kernel(
    const float* __restrict__ cw,
    const float* __restrict__ wf, const float* __restrict__ bif, const float* __restrict__ bhf,
    const float* __restrict__ wb, const float* __restrict__ bib, const float* __restrict__ bhb,
    float* __restrict__ W)
{
    int tid = blockIdx.x * blockDim.x + threadIdx.x;   // 0..4095
    int r = tid >> 6, c = tid & 63;
    const float* x = cw + r * C;

    const float* f_i = wf + (0 * C + c) * C;
    const float* f_g = wf + (2 * C + c) * C;
    const float* f_o = wf + (3 * C + c) * C;
    const float* b_i = wb + (0 * C + c) * C;
    const float* b_g = wb + (2 * C + c) * C;
    const float* b_o = wb + (3 * C + c) * C;

    float zif = 0.f, zgf = 0.f, zof = 0.f, zib = 0.f, zgb = 0.f, zob = 0.f;
    #pragma unroll
    for (int k = 0; k < C; ++k) {
        float xv = x[k];
        zif = fmaf(xv, f_i[k], zif);
        zgf = fmaf(xv, f_g[k], zgf);
        zof = fmaf(xv, f_o[k], zof);
        zib = fmaf(xv, b_i[k], zib);
        zgb = fmaf(xv, b_g[k], zgb);
        zob = fmaf(xv, b_o[k], zob);
    }
    zif += bif[0 * C + c] + bhf[0 * C + c];
    zgf += bif[2 * C + c] + bhf[2 * C + c];
    zof += bif[3 * C + c] + bhf[3 * C + c];
    zib += bib[0 * C + c] + bhb[0 * C + c];
    zgb += bib[2 * C + c] + bhb[2 * C + c];
    zob += bib[3 * C + c] + bhb[3 * C + c];

    float cf = sigf(zif) * tanhf(zgf);
    float hf = sigf(zof) * tanhf(cf);
    float cb = sigf(zib) * tanhf(zgb);
    float hb = sigf(zob) * tanhf(cb);
    W[tid] = fmaxf(hf, hb);
}

// ---- Kernel 2: per-block bucket histogram (LDS atomics only) --------------
__global__ __launch_bounds__(256) void hist_kernel(
    const int* __restrict__ col, int* __restrict__ hist,
    int E, int nbuck, int epb)
{
    __shared__ int h[1024];
    int t = threadIdx.x, b = blockIdx.x;
    for (int i = t; i < nbuck; i += 256) h[i] = 0;
    __syncthreads();
    int base = b * epb;
    int end = min(base + epb, E);
    for (int e = base + t; e < end; e += 256)
        atomicAdd(&h[col[e] >> BSHIFT], 1);
    __syncthreads();
    for (int i = t; i < nbuck; i += 256) hist[b * nbuck + i] = h[i];
}

// ---- Kernel 3: per-bucket exclusive scan over blocks (parallel) -----------
// One block per bucket k: NPART threads scan hist[b][k] over b.
__global__ __launch_bounds__(512) void scan_blocks_kernel(
    int* __restrict__ hist, int* __restrict__ bb, int nbuck)
{
    __shared__ int wsum[8];
    int k = blockIdx.x;
    int b = threadIdx.x;
    int v = hist[b * nbuck + k];
    int lane = b & 63, wid = b >> 6;
    int x = v;
    #pragma unroll
    for (int d = 1; d < 64; d <<= 1) {
        int y = __shfl_up(x, d, 64);
        if (lane >= d) x += y;
    }
    if (lane == 63) wsum[wid] = x;
    __syncthreads();
    if (b == 0) {
        int run = 0;
        #pragma unroll
        for (int w = 0; w < 8; ++w) { int z = wsum[w]; wsum[w] = run; run += z; }
    }
    __syncthreads();
    int excl = x - v + wsum[wid];
    hist[b * nbuck + k] = excl;
    if (b == NPART - 1) bb[k] = excl + v;
}

// ---- Kernel 4: exclusive scan of bucket totals (single block) -------------
__global__ __launch_bounds__(256) void scan_spine_kernel(
    int* __restrict__ bb, int nbuck, int E)
{
    __shared__ int wsum[4];
    int t = threadIdx.x;
    int base = t * 4;
    int v[4];
    #pragma unroll
    for (int j = 0; j < 4; ++j) {
        int idx = base + j;
        v[j] = (idx < nbuck) ? bb[idx] : 0;
    }
    int tsum = v[0] + v[1] + v[2] + v[3];
    int lane = t & 63, wid = t >> 6;
    int x = tsum;
    #pragma unroll
    for (int d = 1; d < 64; d <<= 1) {
        int y = __shfl_up(x, d, 64);
        if (lane >= d) x += y;
    }
    if (lane == 63) wsum[wid] = x;
    __syncthreads();
    if (t == 0) {
        int run = 0;
        #pragma unroll
        for (int w = 0; w < 4; ++w) { int z = wsum[w]; wsum[w] = run; run += z; }
    }
    __syncthreads();
    int run = x - tsum + wsum[wid];
    #pragma unroll
    for (int j = 0; j < 4; ++j) {
        int idx = base + j;
        if (idx < nbuck) bb[idx] = run;
        run += v[j];
    }
    if (t == 0) bb[nbuck] = E;
}

// ---- Kernel 5: partition v2 — LDS counting sort by bucket, coalesced out --
// Each block stages its epb edges sorted-by-bucket in LDS, then streams each
// bucket-run to its reserved global slots (>=64B runs instead of 8B scatter).
__global__ __launch_bounds__(512) void partition_kernel(
    const int* __restrict__ row, const int* __restrict__ col,
    const float* __restrict__ ew, const int* __restrict__ hist,
    const int* __restrict__ bb, int2* __restrict__ payload,
    int E, int nbuck, int epb)
{
    __shared__ int bins[1024];
    __shared__ int base[1024];
    __shared__ int cur[1024];
    __shared__ int hbase[1024];
    __shared__ int2 lpay[EPB_CAP];      // 25.6 KB
    __shared__ ushort karr[EPB_CAP];    // 6.4 KB
    __shared__ int wsum[8];

    int t = threadIdx.x, b = blockIdx.x;
    for (int i = t; i < 1024; i += 512) {
        bins[i] = 0;
        hbase[i] = (i < nbuck) ? hist[b * nbuck + i] : 0;
    }
    __syncthreads();

    int e0 = b * epb;
    int e1 = min(e0 + epb, E);
    for (int e = e0 + t; e < e1; e += 512)
        atomicAdd(&bins[col[e] >> BSHIFT], 1);
    __syncthreads();

    // block-wide exclusive scan of bins[0..1023], 2 bins per thread
    {
        int a = bins[2 * t], b2 = bins[2 * t + 1];
        int s = a + b2;
        int lane = t & 63, wid = t >> 6;
        int x = s;
        #pragma unroll
        for (int d = 1; d < 64; d <<= 1) {
            int y = __shfl_up(x, d, 64);
            if (lane >= d) x += y;
        }
        if (lane == 63) wsum[wid] = x;
        __syncthreads();
        if (t == 0) {
            int run = 0;
            #pragma unroll
            for (int w = 0; w < 8; ++w) { int z = wsum[w]; wsum[w] = run; run += z; }
        }
        __syncthreads();
        int excl = x - s + wsum[wid];
        base[2 * t] = excl;
        base[2 * t + 1] = excl + a;
        cur[2 * t] = excl;
        cur[2 * t + 1] = excl + a;
    }
    __syncthreads();

    // scatter into LDS
    for (int e = e0 + t; e < e1; e += 512) {
        int c = col[e];
        int k = c >> BSHIFT;
        int pos = atomicAdd(&cur[k], 1);
        lpay[pos] = make_int2(row[e] | ((c & (BN - 1)) << 20),
                              __float_as_int(ew[e]));
        karr[pos] = (ushort)k;
    }
    __syncthreads();

    // stream out: consecutive LDS slots -> consecutive global slots per bucket
    int tot = e1 - e0;
    for (int i = t; i < tot; i += 512) {
        int k = karr[i];
        int dst = bb[k] + hbase[k] + (i - base[k]);
        payload[dst] = lpay[i];
    }
}

// ---- Kernel 6: sort_bucket v2 — LDS-staged counting sort by node ----------
// Out: payload2 {row, w*dinv[dst]} sorted by dst node, written coalesced;
//      seg[n]={start,count}; dinv[n] global.
__global__ __launch_bounds__(512) void sort_bucket_kernel(
    const int2* __restrict__ payload, const int* __restrict__ bb,
    int2* __restrict__ payload2, float* __restrict__ dinv,
    int2* __restrict__ seg, int N)
{
    __shared__ int bin[BN];
    __shared__ int bbase[BN];
    __shared__ int cur[BN];
    __shared__ float degl[BN];
    __shared__ float dinvl[BN];
    __shared__ int2 spay[SCAP];         // 32 KB
    int t = threadIdx.x, k = blockIdx.x;
    if (t < BN) { bin[t] = 0; degl[t] = 0.f; }
    __syncthreads();

    int e0 = bb[k], e1 = bb[k + 1];
    for (int e = e0 + t; e < e1; e += 512) {
        int2 p = payload[e];
        int ld = p.x >> 20;
        atomicAdd(&bin[ld], 1);
        atomicAdd(&degl[ld], __int_as_float(p.y));
    }
    __syncthreads();

    // exclusive scan of bin[0..127] in wave 0 (2 bins per lane)
    if (t < 64) {
        int a = bin[2 * t], b2 = bin[2 * t + 1];
        int s = a + b2;
        int x = s;
        #pragma unroll
        for (int d = 1; d < 64; d <<= 1) {
            int y = __shfl_up(x, d, 64);
            if (t >= d) x += y;
        }
        int excl = x - s;
        bbase[2 * t] = excl;
        bbase[2 * t + 1] = excl + a;
    }
    __syncthreads();

    if (t < BN) {
        int n = k * BN + t;
        float di = rsqrtf(degl[t] + 1.0f);    // +1 self-loop weight
        dinvl[t] = di;
        cur[t] = bbase[t];                    // 0-based local cursor
        if (n < N) {
            dinv[n] = di;
            seg[n] = make_int2(e0 + bbase[t], bin[t]);
        }
    }
    __syncthreads();

    int tot = e1 - e0;
    if (tot <= SCAP) {
        // scatter into LDS (payload re-read is L2-hot), then coalesced write
        for (int e = e0 + t; e < e1; e += 512) {
            int2 p = payload[e];
            int ld = p.x >> 20;
            int pos = atomicAdd(&cur[ld], 1);
            spay[pos] = make_int2(p.x & RMASK,
                                  __float_as_int(__int_as_float(p.y) * dinvl[ld]));
        }
        __syncthreads();
        for (int i = t; i < tot; i += 512)
            payload2[e0 + i] = spay[i];
    } else {
        // fallback: direct global scatter (never expected for this data)
        for (int e = e0 + t; e < e1; e += 512) {
            int2 p = payload[e];
            int ld = p.x >> 20;
            int pos = atomicAdd(&cur[ld], 1);
            payload2[e0 + pos] = make_int2(p.x & RMASK,
                                           __float_as_int(__int_as_float(p.y) * dinvl[ld]));
        }
    }
}

// ---- Kernel 7: Xw' = bf16( dinv ⊙ (X @ W) )  (row-scaled, 32 rows/block) --
__global__ __launch_bounds__(256) void gemm_xw_kernel(
    const float* __restrict__ X, const float* __restrict__ W,
    const float* __restrict__ dinv, ushort* __restrict__ Y, int N)
{
    __shared__ float Wl[C * C];
    __shared__ float xl[32][C];
    int t = threadIdx.x;
    #pragma unroll
    for (int i = 0; i < 4; ++i)
        *(float4*)(Wl + 4 * (t + i * 256)) = *(const float4*)(W + 4 * (t + i * 256));

    int n0 = blockIdx.x * 32;
    #pragma unroll
    for (int i = 0; i < 2; ++i) {
        int idx = t + i * 256;            // 0..511 : (row, float4-group)
        int rr = idx >> 4, cc = (idx & 15) << 2;
        int n = n0 + rr;
        float4 v = (n < N) ? *(const float4*)(X + (size_t)n * C + cc)
                           : make_float4(0.f, 0.f, 0.f, 0.f);
        *(float4*)(&xl[rr][cc]) = v;
    }
    __syncthreads();

    int c = t & 63, rb = (t >> 6) * 8;
    float acc[8] = {0.f, 0.f, 0.f, 0.f, 0.f, 0.f, 0.f, 0.f};
    for (int k = 0; k < C; ++k) {
        float w = Wl[k * C + c];
        #pragma unroll
        for (int q = 0; q < 8; ++q) acc[q] = fmaf(xl[rb + q][k], w, acc[q]);
    }
    #pragma unroll
    for (int q = 0; q < 8; ++q) {
        int n = n0 + rb + q;
        if (n < N) Y[(size_t)n * C + c] = f2bf(acc[q] * dinv[n]);  // fold dinv[src]
    }
}

// ---- Kernel 8: gather-reduce, 8 lanes/node, uint4 gathers, 4 edges in flight
// tmp[n] = bf16( ne + ce + dinv[n]*Xw'[n] + sum_seg pn * Xw'[src] )
__global__ __launch_bounds__(256) void reduce_kernel(
    const int2* __restrict__ seg, const int2* __restrict__ payload2,
    const ushort* __restrict__ Xw, const float* __restrict__ dinv,
    const float* __restrict__ ne, const float* __restrict__ ce,
    ushort* __restrict__ tmpb, int N)
{
    int t = blockIdx.x * 256 + threadIdx.x;
    int n = t >> 3;
    if (n >= N) return;
    int cs = (t & 7) << 3;                 // channel offset (8 channels/lane)

    int2 s = seg[n];
    int p = s.x, cnt = s.y;
    float a[8] = {0.f, 0.f, 0.f, 0.f, 0.f, 0.f, 0.f, 0.f};
    while (cnt >= 4) {
        int2 p0 = payload2[p];
        int2 p1 = payload2[p + 1];
        int2 p2 = payload2[p + 2];
        int2 p3 = payload2[p + 3];
        uint4 u0 = *(const uint4*)(Xw + (size_t)p0.x * C + cs);
        uint4 u1 = *(const uint4*)(Xw + (size_t)p1.x * C + cs);
        uint4 u2 = *(const uint4*)(Xw + (size_t)p2.x * C + cs);
        uint4 u3 = *(const uint4*)(Xw + (size_t)p3.x * C + cs);
        bf8fma(u0, __int_as_float(p0.y), a);
        bf8fma(u1, __int_as_float(p1.y), a);
        bf8fma(u2, __int_as_float(p2.y), a);
        bf8fma(u3, __int_as_float(p3.y), a);
        p += 4; cnt -= 4;
    }
    while (cnt > 0) {
        int2 pl = payload2[p];
        uint4 u = *(const uint4*)(Xw + (size_t)pl.x * C + cs);
        bf8fma(u, __int_as_float(pl.y), a);
        ++p; --cnt;
    }
    float di = dinv[n];
    size_t o = (size_t)n * C + cs;
    uint4 ux = *(const uint4*)(Xw + o);     // Xw' = dinv[n]*(X@W)[n]
    bf8fma(ux, di, a);
    const float4 nv0 = *(const float4*)(ne + o);
    const float4 nv1 = *(const float4*)(ne + o + 4);
    const float4 cv0 = *(const float4*)(ce + o);
    const float4 cv1 = *(const float4*)(ce + o + 4);
    a[0] += nv0.x + cv0.x;  a[1] += nv0.y + cv0.y;
    a[2] += nv0.z + cv0.z;  a[3] += nv0.w + cv0.w;
    a[4] += nv1.x + cv1.x;  a[5] += nv1.y + cv1.y;
    a[6] += nv1.z + cv1.z;  a[7] += nv1.w + cv1.w;

    uint4 w;
    w.x = (uint)f2bf(a[0]) | ((uint)f2bf(a[1]) << 16);
    w.y = (uint)f2bf(a[2]) | ((uint)f2bf(a[3]) << 16);
    w.z = (uint)f2bf(a[4]) | ((uint)f2bf(a[5]) << 16);
    w.w = (uint)f2bf(a[6]) | ((uint)f2bf(a[7]) << 16);
    *(uint4*)(tmpb + o) = w;
}

// ---- Kernel 9: out = tmp @ fW^T + fb  (32 rows/block, bf16 tmp input) -----
__global__ __launch_bounds__(256) void fusion_kernel(
    const ushort* __restrict__ tmpb, const float* __restrict__ fW,
    const float* __restrict__ fb, float* __restrict__ out, int N)
{
    __shared__ float Wt[C][C + 1];   // Wt[k][j] = fW[j*C+k]
    __shared__ float tl[32][C];
    int t = threadIdx.x;
    #pragma unroll
    for (int i = 0; i < 16; ++i) {
        int idx = t + i * 256;
        Wt[idx & 63][idx >> 6] = fW[idx];
    }
    int n0 = blockIdx.x * 32;
    {
        int rr = t >> 3, cs = (t & 7) << 3;
        int n = n0 + rr;
        uint4 u = (n < N) ? *(const uint4*)(tmpb + (size_t)n * C + cs)
                          : make_uint4(0u, 0u, 0u, 0u);
        tl[rr][cs + 0] = __uint_as_float(u.x << 16);
        tl[rr][cs + 1] = __uint_as_float(u.x & 0xffff0000u);
        tl[rr][cs + 2] = __uint_as_float(u.y << 16);
        tl[rr][cs + 3] = __uint_as_float(u.y & 0xffff0000u);
        tl[rr][cs + 4] = __uint_as_float(u.z << 16);
        tl[rr][cs + 5] = __uint_as_float(u.z & 0xffff0000u);
        tl[rr][cs + 6] = __uint_as_float(u.w << 16);
        tl[rr][cs + 7] = __uint_as_float(u.w & 0xffff0000u);
    }
    __syncthreads();

    int j = t & 63, rb = (t >> 6) * 8;
    float bj = fb[j];
    float acc[8] = {bj, bj, bj, bj, bj, bj, bj, bj};
    for (int k = 0; k < C; ++k) {
        float w = Wt[k][j];
        #pragma unroll
        for (int q = 0; q < 8; ++q) acc[q] = fmaf(tl[rb + q][k], w, acc[q]);
    }
    #pragma unroll
    for (int q = 0; q < 8; ++q) {
        int n = n0 + rb + q;
        if (n < N) out[(size_t)n * C + j] = acc[q];
    }
}

extern "C" void kernel_launch(void* const* d_in, const int* in_sizes, int n_in,
                              void* d_out, int out_size, void* d_ws, size_t ws_size,
                              hipStream_t stream)
{
    const float* X        = (const float*)d_in[0];
    const int*   ei       = (const int*)d_in[1];
    const float* ew       = (const float*)d_in[2];
    const float* node_emb = (const float*)d_in[3];
    const float* com_emb  = (const float*)d_in[4];
    const float* cw       = (const float*)d_in[5];
    const float* w_ih_f   = (const float*)d_in[6];
    const float* b_ih_f   = (const float*)d_in[7];
    const float* b_hh_f   = (const float*)d_in[8];
    const float* w_ih_b   = (const float*)d_in[9];
    const float* b_ih_b   = (const float*)d_in[10];
    const float* b_hh_b   = (const float*)d_in[11];
    const float* fW       = (const float*)d_in[12];
    const float* fb       = (const float*)d_in[13];
    float* out = (float*)d_out;

    const int N = in_sizes[0] / C;
    const int E = in_sizes[2];
    const int* row = ei;               // edge_index[0]
    const int* col = ei + E;           // edge_index[1]
    const int nbuck = (N + BN - 1) / BN;
    const int epb = (E + NPART - 1) / NPART;   // 3125 <= EPB_CAP

    // ---- workspace layout ----
    // [W][dinv][bb][seg][payload2: E*8][big: max(E*8 + hist, N*C*2)]
    // pass-1 payload + hist alias INTO big (dead before reduce writes tmpb).
    // Xw' (bf16) lives in d_out until fusion overwrites it.
    char* wsb = (char*)d_ws;
    size_t o = 0;
    auto alloc = [&](size_t bytes) { void* p = wsb + o; o = (o + bytes + 15) & ~(size_t)15; return p; };
    float* W        = (float*)alloc((size_t)C * C * sizeof(float));      // 16 KB
    float* dinv     = (float*)alloc((size_t)N * sizeof(float));          // 400 KB
    int*   bb       = (int*)  alloc((size_t)(nbuck + 1) * sizeof(int));  // 3 KB
    int2*  seg      = (int2*) alloc((size_t)N * sizeof(int2));           // 800 KB
    int2*  payload2 = (int2*) alloc((size_t)E * sizeof(int2));           // 12.8 MB
    size_t big_bytes_a = (size_t)E * 8 + (size_t)NPART * nbuck * 4;      // payload+hist
    size_t big_bytes_b = (size_t)N * C * 2;                              // tmpb
    char*  big      = (char*)alloc(big_bytes_a > big_bytes_b ? big_bytes_a : big_bytes_b);
    int2*  payload  = (int2*)big;
    int*   hist     = (int*)(big + (size_t)E * 8);
    ushort* tmpb    = (ushort*)big;
    ushort* Xw      = (ushort*)out;    // d_out holds bf16 Xw' until fusion overwrites

    lstm_w_kernel<<<(C * C) / 256, 256, 0, stream>>>(
        cw, w_ih_f, b_ih_f, b_hh_f, w_ih_b, b_ih_b, b_hh_b, W);

    hist_kernel<<<NPART, 256, 0, stream>>>(col, hist, E, nbuck, epb);
    scan_blocks_kernel<<<nbuck, 512, 0, stream>>>(hist, bb, nbuck);
    scan_spine_kernel<<<1, 256, 0, stream>>>(bb, nbuck, E);
    partition_kernel<<<NPART, 512, 0, stream>>>(
        row, col, ew, hist, bb, payload, E, nbuck, epb);

    sort_bucket_kernel<<<nbuck, 512, 0, stream>>>(
        payload, bb, payload2, dinv, seg, N);

    gemm_xw_kernel<<<(N + 31) / 32, 256, 0, stream>>>(X, W, dinv, Xw, N);

    reduce_kernel<<<(N * 8 + 255) / 256, 256, 0, stream>>>(
        seg, payload2, Xw, dinv, node_emb, com_emb, tmpb, N);

    fusion_kernel<<<(N + 31) / 32, 256, 0, stream>>>(tmpb, fW, fb, out, N);
}